// Round 5
// baseline (1811.846 us; speedup 1.0000x reference)
//
#include <hip/hip_runtime.h>
#include <math.h>

#define S_   56
#define B_   32
#define C_   1024
#define T_   48
#define TS   47
#define H_   1024
#define EMB_ 512
#define RANK_ 128
#define VOCAB_ 32000
#define G4   4096
#define NBLK 256

using bf16x8 = __attribute__((ext_vector_type(8))) __bf16;
using f32x4  = __attribute__((ext_vector_type(4))) float;

__device__ __forceinline__ float sigmoidf_(float x){ return 1.0f/(1.0f+expf(-x)); }
__device__ __forceinline__ float b2f(__bf16 x){ return (float)x; }
__device__ __forceinline__ f32x4 z4(){ f32x4 z = {0.f,0.f,0.f,0.f}; return z; }

// ---------- device-coherent (MALL write-through) store helpers ----------
#define AG __HIP_MEMORY_SCOPE_AGENT
__device__ __forceinline__ void stc_bf16(__bf16* p, __bf16 v){
  union { __bf16 b; unsigned short s; } t; t.b = v;
  __hip_atomic_store((unsigned short*)p, t.s, __ATOMIC_RELAXED, AG);
}
__device__ __forceinline__ void stc_f32(float* p, float v){
  __hip_atomic_store(p, v, __ATOMIC_RELAXED, AG);
}

// ---------------- shared-memory structures for the persistent kernel ----------------
struct RedShared {
  float red[4][2][16][18];    // 9216 B
  float pS2[2048];            // 8192 B : p_att[t-1] staged (32 b x 64)
};
struct AttnShared {
  float hS[1024];
  float sS[64];
  float pS[64];
};
union alignas(16) SharedU { RedShared r; AttnShared a; };

// ---------------- split grid barrier (16 groups x 16 arrivals) ----------------
__device__ __forceinline__ void bar_arrive(unsigned* bars, int bi, unsigned e){
  asm volatile("s_waitcnt vmcnt(0)" ::: "memory");
  __syncthreads();
  if (threadIdx.x == 0){
    unsigned* grp = bars + 32*(1 + (bi & 15));
    unsigned old = __hip_atomic_fetch_add(grp, 1u, __ATOMIC_RELAXED, AG);
    if (old == 16u*e - 1u)
      __hip_atomic_fetch_add(bars, 1u, __ATOMIC_RELAXED, AG);
  }
}
__device__ __forceinline__ void bar_wait(unsigned* bars, unsigned e){
  if (threadIdx.x == 0){
    while (__hip_atomic_load(bars, __ATOMIC_RELAXED, AG) < 16u*e)
      __builtin_amdgcn_s_sleep(1);
  }
  __syncthreads();
  asm volatile("" ::: "memory");
}
__device__ __forceinline__ void flag_wait(unsigned* cc, unsigned tgt){
  if (threadIdx.x == 0){
    while (__hip_atomic_load(cc, __ATOMIC_RELAXED, AG) < tgt)
      __builtin_amdgcn_s_sleep(1);
  }
  __syncthreads();
  asm volatile("" ::: "memory");
}

// ---------------- init ----------------
__global__ void k_init(const float* __restrict__ es, __bf16* h0bm1, __bf16* fm1,
                       float* pbufm1, unsigned* bars){
  int i = blockIdx.x*blockDim.x + threadIdx.x;
  if (i < 32*H_){
    int b = i >> 10, j = i & 1023;
    h0bm1[(size_t)b*1024 + j] = (__bf16)es[i];           // h0 <- es[0]
    fm1[(size_t)b*2048 + j]   = (__bf16)es[32*H_ + i];   // h1 <- es[1]
  }
  if (i < 2048) pbufm1[i] = 0.f;                         // p_att[-1] = 0 -> ctx0 = 0
  if (i < 1024) bars[i] = 0u;
}

// ---------------- fp32 -> bf16 ----------------
__global__ void k_cvt(const float* __restrict__ src, __bf16* __restrict__ dst, int n){
  int i = (blockIdx.x*blockDim.x + threadIdx.x)*4;
  if (i < n){
    float4 v = *(const float4*)(src + i);
    dst[i+0]=(__bf16)v.x; dst[i+1]=(__bf16)v.y; dst[i+2]=(__bf16)v.z; dst[i+3]=(__bf16)v.w;
  }
}

// ---------------- embedding ----------------
__global__ void k_embed(const float* __restrict__ E, const float* __restrict__ P,
                        const int* __restrict__ tok, __bf16* __restrict__ embb){
  int blk = blockIdx.x;            // t*32+b
  int t = blk >> 5, b = blk & 31, tid = threadIdx.x;   // 128 threads
  __shared__ float er[RANK_];
  int tk = tok[b*T_ + t];
  er[tid] = E[(size_t)tk*RANK_ + tid];
  __syncthreads();
  float4 acc = {0.f,0.f,0.f,0.f};
  int e = tid*4;
  for (int r2 = 0; r2 < RANK_; r2++){
    float ev = er[r2];
    float4 p = *(const float4*)(P + (size_t)r2*EMB_ + e);
    acc.x += ev*p.x; acc.y += ev*p.y; acc.z += ev*p.z; acc.w += ev*p.w;
  }
  size_t o = (size_t)blk*EMB_ + e;
  embb[o+0]=(__bf16)acc.x; embb[o+1]=(__bf16)acc.y;
  embb[o+2]=(__bf16)acc.z; embb[o+3]=(__bf16)acc.w;
}

// ---------------- pack rows into per-block LDS-resident frag order ----------------
// dst[((bi*NCH + ch0+bx)*64 + (aq*16 + g*4 + q))*8 + i] = M[bx*32 + aq*8 + i][g*1024 + bi*4 + q]
__global__ void k_pack2(const float* __restrict__ A, int K1, const float* __restrict__ Bsrc,
                        __bf16* __restrict__ dst, int NCH, int ch0){
  int bx = blockIdx.x;            // k-chunk within this segment (32 rows)
  int g  = blockIdx.y >> 2;       // gate 0..3
  int band = blockIdx.y & 3;      // 256-col band within the gate
  int tid = threadIdx.x;          // 256 threads
  __shared__ __bf16 Tl[32][264];
  {
    int r = tid>>3, cs = tid&7;   // row, col-octet (32 cols each)
    int kk = bx*32 + r;
    const float* src = (kk < K1) ? (A + (size_t)kk*G4 + g*1024 + band*256 + cs*32)
                                 : (Bsrc + (size_t)(kk-K1)*G4 + g*1024 + band*256 + cs*32);
    #pragma unroll
    for (int u=0;u<8;u++){
      float4 v = *(const float4*)(src + u*4);
      Tl[r][cs*32+u*4+0]=(__bf16)v.x; Tl[r][cs*32+u*4+1]=(__bf16)v.y;
      Tl[r][cs*32+u*4+2]=(__bf16)v.z; Tl[r][cs*32+u*4+3]=(__bf16)v.w;
    }
  }
  __syncthreads();
  int bil = tid>>2, aq = tid&3;   // 64 local blocks x 4 k-quarters
  int bi = band*64 + bil;
  int ch = ch0 + bx;
  #pragma unroll
  for (int q=0;q<4;q++){
    __bf16 o8[8];
    #pragma unroll
    for (int i=0;i<8;i++) o8[i] = Tl[aq*8+i][bil*4+q];
    int lane = aq*16 + g*4 + q;
    *(bf16x8*)(dst + (((size_t)bi*NCH + ch)*64 + lane)*8) = *(bf16x8*)o8;
  }
}

// ---------------- generic B-frag pack (16x16x32) for Wo / P^T ----------------
__global__ void k_packB(const float* __restrict__ src, __bf16* __restrict__ dst,
                        int K, int N, int tr){
  int kk0 = blockIdx.x*32, j0 = blockIdx.y*16, lane = threadIdx.x;  // 64 threads
  int am = lane&15, aq = lane>>4;
  int j = j0 + am;
  __bf16 o8[8];
  #pragma unroll
  for (int i=0;i<8;i++){
    int k = kk0 + aq*8 + i;
    float v = tr ? src[(size_t)j*K + k] : src[(size_t)k*N + j];
    o8[i] = (__bf16)v;
  }
  int NCH = K/32, jt = j0>>4, ch = kk0>>5;
  *(bf16x8*)(dst + (((size_t)jt*NCH + ch)*64 + lane)*8) = *(bf16x8*)o8;
}

// ---------------- one-time encW = enc @ W0_ctx  (M=1792, K=1024, N=4096) ----------------
// output layout: encWp[((bi*32 + b)*16 + g*4+q)*56 + s]   (bi = gate-col block, 57KB/bi)
__global__ __launch_bounds__(256) void k_encw(
    const float* __restrict__ W0, const __bf16* __restrict__ encb,
    __bf16* __restrict__ encWp)
{
  __shared__ __bf16 Bl[8*16*64*8];   // 128 KB: [jt(8)][ch(16)][lane(64)][8]
  int mg = blockIdx.x, ng = blockIdx.y, tid = threadIdx.x;  // grid (14, 32)
  int w = tid>>6, lane = tid&63, am = lane&15, aq = lane>>4;
  int m0 = mg*128, j0 = ng*128;
  f32x4 acc[8][2];
  #pragma unroll
  for (int i=0;i<8;i++){ acc[i][0]=z4(); acc[i][1]=z4(); }
  for (int h=0; h<2; h++){
    __syncthreads();
    for (int idx = tid; idx < 8192; idx += 256){
      int row = idx >> 4, seg = idx & 15;
      const float* src = W0 + (size_t)(512 + h*512 + row)*G4 + j0 + seg*8;
      float4 v0 = *(const float4*)src;
      float4 v1 = *(const float4*)(src+4);
      int ch = row >> 5, r5 = row & 31;
      int aq2 = r5 >> 3, i8 = r5 & 7;
      int jtl = seg >> 1, amb = (seg & 1)*8;
      __bf16* d = Bl + (((size_t)jtl*16 + ch)*64 + aq2*16 + amb)*8 + i8;
      float vv[8] = {v0.x,v0.y,v0.z,v0.w,v1.x,v1.y,v1.z,v1.w};
      #pragma unroll
      for (int u=0;u<8;u++) d[u*8] = (__bf16)vv[u];
    }
    __syncthreads();
    int jt2 = w*2;
    #pragma unroll
    for (int mt=0; mt<8; mt++){
      const __bf16* ap = encb + (size_t)(m0 + mt*16 + am)*1024 + h*512 + aq*8;
      #pragma unroll
      for (int ch=0; ch<16; ch++){
        bf16x8 a  = *(const bf16x8*)(ap + ch*32);
        bf16x8 bA = *(const bf16x8*)(Bl + (((size_t)jt2*16 + ch)*64 + lane)*8);
        bf16x8 bB = *(const bf16x8*)(Bl + (((size_t)(jt2+1)*16 + ch)*64 + lane)*8);
        acc[mt][0] = __builtin_amdgcn_mfma_f32_16x16x32_bf16(a, bA, acc[mt][0], 0,0,0);
        acc[mt][1] = __builtin_amdgcn_mfma_f32_16x16x32_bf16(a, bB, acc[mt][1], 0,0,0);
      }
    }
  }
  #pragma unroll
  for (int mt=0; mt<8; mt++){
    #pragma unroll
    for (int jj=0; jj<2; jj++){
      int jcol = j0 + (w*2+jj)*16 + am;
      int biW = (jcol & 1023) >> 2;
      int gq  = ((jcol >> 10) << 2) | (jcol & 3);
      #pragma unroll
      for (int rg=0; rg<4; rg++){
        int m = m0 + mt*16 + aq*4 + rg;
        int b = m & 31, s = m >> 5;
        encWp[((size_t)(biW*32 + b)*16 + gq)*56 + s] = (__bf16)acc[mt][jj][rg];
      }
    }
  }
}

// ---------------- chunk accumulate: NC chunks of K=32 against LDS weights ----------------
template<int NC>
__device__ __forceinline__ void accum(f32x4& acc0, f32x4& acc1,
    const __bf16* __restrict__ abase, int rs, const __bf16* wlds,
    int ch0, int am, int aq, int lane)
{
  const __bf16* a0p = abase + (size_t)am*rs + aq*8;
  const __bf16* a1p = abase + (size_t)(am+16)*rs + aq*8;
  const __bf16* wl  = wlds + (size_t)lane*8;
  #pragma unroll
  for (int c=0;c<NC;c++){
    int ch = ch0 + c;
    bf16x8 a0 = *(const bf16x8*)(a0p + (size_t)ch*32);
    bf16x8 a1 = *(const bf16x8*)(a1p + (size_t)ch*32);
    bf16x8 w  = *(const bf16x8*)(wl  + (size_t)ch*512);
    acc0 = __builtin_amdgcn_mfma_f32_16x16x32_bf16(a0, w, acc0, 0, 0, 0);
    acc1 = __builtin_amdgcn_mfma_f32_16x16x32_bf16(a1, w, acc1, 0, 0, 0);
  }
}

// ---------------- 8-wave reduce + LSTM cell; GCTX adds p_att @ encW slice ----------------
template<bool GCTX>
__device__ __forceinline__ void reduce_cell(SharedU& su, const f32x4& acc0, const f32x4& acc1,
    int bi, int tid, const float* __restrict__ bias, float& creg,
    __bf16* __restrict__ hout, int stride, const __bf16* __restrict__ encWb)
{
  int kw = tid>>6, lane = tid&63, am = lane&15, aq = lane>>4;
  if (kw >= 4){
    #pragma unroll
    for (int rg=0;rg<4;rg++){
      su.r.red[kw-4][0][aq*4+rg][am] = acc0[rg];
      su.r.red[kw-4][1][aq*4+rg][am] = acc1[rg];
    }
  }
  __syncthreads();
  if (kw < 4){
    #pragma unroll
    for (int rg=0;rg<4;rg++){
      su.r.red[kw][0][aq*4+rg][am] += acc0[rg];
      su.r.red[kw][1][aq*4+rg][am] += acc1[rg];
    }
  }
  __syncthreads();
  if (tid < 128){
    int b = tid>>2, q = tid&3;
    int mt = b>>4, r = b&15;
    float G0=0.f, G1=0.f, G2=0.f, G3=0.f;
    #pragma unroll
    for (int w2=0; w2<4; w2++){
      G0 += su.r.red[w2][mt][r][q];
      G1 += su.r.red[w2][mt][r][4+q];
      G2 += su.r.red[w2][mt][r][8+q];
      G3 += su.r.red[w2][mt][r][12+q];
    }
    if (GCTX){
      const __bf16* eb = encWb + (size_t)b*896 + q*56;  // row (b, g*4+q), g-stride 224
      float d0=0.f,d1=0.f,d2=0.f,d3=0.f;
      #pragma unroll
      for (int s0=0; s0<56; s0+=8){
        bf16x8 e0 = *(const bf16x8*)(eb + s0);
        bf16x8 e1 = *(const bf16x8*)(eb + 224 + s0);
        bf16x8 e2 = *(const bf16x8*)(eb + 448 + s0);
        bf16x8 e3 = *(const bf16x8*)(eb + 672 + s0);
        #pragma unroll
        for (int u=0;u<8;u++){
          float p = su.r.pS2[b*64 + s0 + u];
          d0 += p*b2f(e0[u]); d1 += p*b2f(e1[u]);
          d2 += p*b2f(e2[u]); d3 += p*b2f(e3[u]);
        }
      }
      G0 += d0; G1 += d1; G2 += d2; G3 += d3;
    }
    int j = bi*4 + q;
    float gi = G0 + bias[j];
    float gf = G1 + bias[1024 + j];
    float gg = G2 + bias[2048 + j];
    float go = G3 + bias[3072 + j];
    float ii = sigmoidf_(gi), ff = sigmoidf_(gf), gv = tanhf(gg), oo = sigmoidf_(go);
    float cv = ff*creg + ii*gv;
    float hv = oo*tanhf(cv);
    creg = cv;
    stc_bf16(hout + (size_t)b*stride + j, (__bf16)hv);
  }
}

// ---------------- attention: scores + softmax only -> p_att (512 threads) ----------------
__device__ __forceinline__ void attn_block(AttnShared& sa, int b, int tid,
    const __bf16* __restrict__ encb, const int* __restrict__ enc_lens,
    const __bf16* __restrict__ fbt, float* __restrict__ pbt)
{
  if (tid < 128){
    bf16x8 h8 = *(const bf16x8*)(fbt + (size_t)b*2048 + tid*8);
    #pragma unroll
    for (int u=0;u<8;u++) sa.hS[tid*8+u] = b2f(h8[u]);
  }
  __syncthreads();
  int w = tid >> 6, lane = tid & 63;
  for (int s = w; s < S_; s += 8){
    const __bf16* er = encb + ((size_t)s*32 + b)*C_;
    float a = 0.f;
    #pragma unroll
    for (int half = 0; half < 2; half++){
      int k = lane*8 + half*512;
      bf16x8 e8 = *(const bf16x8*)(er + k);
      #pragma unroll
      for (int u=0;u<8;u++) a += b2f(e8[u]) * sa.hS[k+u];
    }
    #pragma unroll
    for (int off=32; off>0; off>>=1) a += __shfl_down(a, off);
    if (lane == 0) sa.sS[s] = a;
  }
  __syncthreads();
  if (tid < 64){
    int len = enc_lens[b];
    float sc = (tid < len && tid < S_) ? sa.sS[tid] : -1e30f;
    float m = sc;
    #pragma unroll
    for (int off=32; off>0; off>>=1) m = fmaxf(m, __shfl_xor(m, off));
    float e = expf(sc - m);
    float ssum = e;
    #pragma unroll
    for (int off=32; off>0; off>>=1) ssum += __shfl_xor(ssum, off);
    if (tid < 56) stc_f32(pbt + b*64 + tid, e / ssum);
  }
}

// ---------------- persistent decode loop (256 blocks x 512 threads) ----------------
__global__ __launch_bounds__(512) void k_loop(
    const __bf16* __restrict__ WP0, const __bf16* __restrict__ WP1,
    const float* __restrict__ b0, const float* __restrict__ b1,
    __bf16* __restrict__ h0b, __bf16* __restrict__ featsb,
    const __bf16* __restrict__ embb,
    const __bf16* __restrict__ encb, const int* __restrict__ enc_lens,
    const __bf16* __restrict__ encWp, float* __restrict__ pbuf0,
    unsigned* bars)
{
  __shared__ __bf16 wB0[48*512];   // 49152 B : [emb(16ch) | h0(32ch)] x N=16 gate-cols
  __shared__ __bf16 wB1[64*512];   // 65536 B : [h0(32ch)  | h1(32ch)]
  __shared__ SharedU su;           // 17408 B
  int bi = blockIdx.x, tid = threadIdx.x;
  int kw = tid>>6, lane = tid&63, am = lane&15, aq = lane>>4;
  unsigned* ctxcnt = bars + 768;
  const __bf16* encWb = encWp + (size_t)bi*28672;   // 32*16*56

  {
    const bf16x8* g0 = (const bf16x8*)(WP0 + (size_t)bi*48*512);
    const bf16x8* g1 = (const bf16x8*)(WP1 + (size_t)bi*64*512);
    bf16x8* l0 = (bf16x8*)wB0;
    bf16x8* l1 = (bf16x8*)wB1;
    for (int idx = tid; idx < 48*64; idx += 512) l0[idx] = g0[idx];
    for (int idx = tid; idx < 64*64; idx += 512) l1[idx] = g1[idx];
  }
  __syncthreads();

  float c0r = 0.f, c1r = 0.f;
  f32x4 g00 = z4(), g01 = z4(), g10 = z4(), g11 = z4();

  // prologue: gates0(t=0) partial = emb_0 @ W0e + h0_init @ U0
  accum<2>(g00, g01, embb,                 512,  wB0, kw*2,    am, aq, lane);
  accum<4>(g00, g01, h0b - 32768 - 512,    1024, wB0, 16+kw*4, am, aq, lane);

  unsigned e = 0;
  for (int t = 0; t < TS; t++){
    const __bf16* fprev = featsb + ((size_t)(t-1))*65536;
    __bf16* h0t = h0b + (size_t)t*32768;
    __bf16* ft  = featsb + (size_t)t*65536;

    // ---- phase 1: gctx(p_att[t-1] @ encW) + gates0 -> cell0 -> h0_t ----
    flag_wait(ctxcnt, 32u*t);
    {
      const float* pprev = pbuf0 + (size_t)t*2048;   // slot t-1
      for (int i = tid; i < 2048; i += 512) su.r.pS2[i] = pprev[i];
    }
    reduce_cell<true>(su, g00, g01, bi, tid, b0, c0r, h0t, 1024, encWb);
    g00 = z4(); g01 = z4();
    bar_arrive(bars, bi, ++e);
    accum<4>(g10, g11, fprev - 1024, 2048, wB1, 32+kw*4, am, aq, lane);  // U1 @ h1_{t-1}
    bar_wait(bars, e);

    // ---- phase 2: + W1 @ h0_t -> gates1 -> cell1 -> h1_t ----
    accum<4>(g10, g11, h0t, 1024, wB1, kw*4, am, aq, lane);
    reduce_cell<false>(su, g10, g11, bi, tid, b1, c1r, ft, 2048, (const __bf16*)nullptr);
    g10 = z4(); g11 = z4();
    bar_arrive(bars, bi, ++e);
    if (t + 1 < TS){
      accum<2>(g00, g01, embb + (size_t)(t+1)*16384, 512,  wB0, kw*2,    am, aq, lane);
      accum<4>(g00, g01, h0t - 512,                  1024, wB0, 16+kw*4, am, aq, lane);
    }
    bar_wait(bars, e);

    // ---- phase 3: attention scores+softmax (32 blocks) -> p_att[t] + flag ----
    if (bi < 32){
      attn_block(su.a, bi, tid, encb, enc_lens, ft, pbuf0 + (size_t)(t+1)*2048);
      asm volatile("s_waitcnt vmcnt(0)" ::: "memory");
      __syncthreads();
      if (tid == 0) __hip_atomic_fetch_add(ctxcnt, 1u, __ATOMIC_RELAXED, AG);
    }
  }
}

// ---------------- post-loop: ctx_t = p_att[t] @ enc  -> featsb[t]+1024 ----------------
__global__ __launch_bounds__(256) void k_ctx(
    const __bf16* __restrict__ encb, const float* __restrict__ pbuf0,
    __bf16* __restrict__ featsb)
{
  __shared__ __bf16 encL[56*1024];   // 114688 B
  __shared__ float pL[64];
  int b = blockIdx.x, tid = threadIdx.x;
  for (int i = tid*8; i < 56*1024; i += 256*8){
    int s = i >> 10, c = i & 1023;
    *(bf16x8*)(encL + i) = *(const bf16x8*)(encb + ((size_t)s*32 + b)*C_ + c);
  }
  for (int t = 0; t < TS; t++){
    __syncthreads();
    if (tid < 56) pL[tid] = pbuf0[(size_t)(t+1)*2048 + b*64 + tid];
    __syncthreads();
    int c0 = tid*4;
    float a0=0.f,a1=0.f,a2=0.f,a3=0.f;
    for (int s=0;s<56;s++){
      float p = pL[s];
      const __bf16* er = encL + s*1024 + c0;
      a0 += p*b2f(er[0]); a1 += p*b2f(er[1]); a2 += p*b2f(er[2]); a3 += p*b2f(er[3]);
    }
    __bf16* d = featsb + (size_t)t*65536 + (size_t)b*2048 + 1024 + c0;
    d[0]=(__bf16)a0; d[1]=(__bf16)a1; d[2]=(__bf16)a2; d[3]=(__bf16)a3;
  }
}

// ---------------- hproj = tanh(featsb @ WoP + bo) -> hpb (bf16 MFMA) ----------------
__global__ __launch_bounds__(256) void k_hproj_mfma(
    const __bf16* __restrict__ fb, const __bf16* __restrict__ WoP,
    const float* __restrict__ bo, __bf16* __restrict__ hpb)
{
  int nt = blockIdx.x, jb = blockIdx.y, tid = threadIdx.x;  // (47,16)
  int w = tid>>6, lane = tid&63;
  int mt = w&1, jw = w>>1;
  int am = lane&15, aq = lane>>4;
  const __bf16* aRow = fb + ((size_t)(nt*32 + mt*16 + am))*2048 + aq*8;
  int jt = jb*2 + jw;
  const __bf16* bptr = WoP + ((size_t)jt*64)*512 + lane*8;
  f32x4 acc = {0,0,0,0};
  bf16x8 ar0 = *(const bf16x8*)(aRow);
  bf16x8 br0 = *(const bf16x8*)(bptr);
  bf16x8 ar1 = *(const bf16x8*)(aRow + 32);
  bf16x8 br1 = *(const bf16x8*)(bptr + 512);
  for (int ch = 0; ch < 64; ch += 2){
    bf16x8 a0 = ar0, b0 = br0, a1 = ar1, b1 = br1;
    if (ch + 2 < 64){
      ar0 = *(const bf16x8*)(aRow + (ch+2)*32);
      br0 = *(const bf16x8*)(bptr + (size_t)(ch+2)*512);
      ar1 = *(const bf16x8*)(aRow + (ch+3)*32);
      br1 = *(const bf16x8*)(bptr + (size_t)(ch+3)*512);
    }
    acc = __builtin_amdgcn_mfma_f32_16x16x32_bf16(a0, b0, acc, 0, 0, 0);
    acc = __builtin_amdgcn_mfma_f32_16x16x32_bf16(a1, b1, acc, 0, 0, 0);
  }
  int jcol = jb*32 + jw*16 + am;
  float bv = bo[jcol];
  #pragma unroll
  for (int rg=0; rg<4; rg++){
    int m = nt*32 + mt*16 + aq*4 + rg;
    hpb[(size_t)m*512 + jcol] = (__bf16)tanhf(acc[rg] + bv);
  }
}

// ---------------- r = hpb @ P^T -> rbuf (bf16 MFMA) ----------------
__global__ __launch_bounds__(256) void k_rproj_mfma(
    const __bf16* __restrict__ hpb, const __bf16* __restrict__ PP,
    __bf16* __restrict__ rb)
{
  int nt = blockIdx.x, jb = blockIdx.y, tid = threadIdx.x;  // (47,4)
  int w = tid>>6, lane = tid&63;
  int mt = w&1, jw = w>>1;
  int am = lane&15, aq = lane>>4;
  const __bf16* aRow = hpb + ((size_t)(nt*32 + mt*16 + am))*512 + aq*8;
  int jt = jb*2 + jw;
  const __bf16* bptr = PP + ((size_t)jt*16)*512 + lane*8;
  f32x4 acc = {0,0,0,0};
  #pragma unroll
  for (int ch = 0; ch < 16; ch++){
    bf16x8 a = *(const bf16x8*)(aRow + ch*32);
    bf16x8 b = *(const bf16x8*)(bptr + (size_t)ch*512);
    acc = __builtin_amdgcn_mfma_f32_16x16x32_bf16(a, b, acc, 0, 0, 0);
  }
  int jcol = jb*32 + jw*16 + am;
  #pragma unroll
  for (int rg=0; rg<4; rg++){
    int m = nt*32 + mt*16 + aq*4 + rg;
    rb[(size_t)m*RANK_ + jcol] = (__bf16)acc[rg];
  }
}

// ---------------- vocab GEMM: grid 250 v-chunks, loop all 47 n-tiles ----------------
__global__ __launch_bounds__(256) void k_vocab2(
    const __bf16* __restrict__ rb, const __bf16* __restrict__ Eb,
    const int* __restrict__ tok,
    float* __restrict__ mpart, float* __restrict__ lpart,
    float* __restrict__ lablog)
{
  int vc = blockIdx.x, tid = threadIdx.x;
  int w = tid>>6, lane = tid&63;
  int am = lane&15, aq = lane>>4;
  int vb = vc*128 + w*32;
  bf16x8 bfr[2][4];
  #pragma unroll
  for (int vt=0; vt<2; vt++)
    #pragma unroll
    for (int ks=0; ks<4; ks++)
      bfr[vt][ks] = *(const bf16x8*)(Eb + ((size_t)(vb + vt*16 + am))*RANK_ + ks*32 + aq*8);

  __shared__ float redM[4][32], redL[4][32];
  for (int nt = 0; nt < TS; nt++){
    f32x4 acc[2][2] = {{{0,0,0,0},{0,0,0,0}},{{0,0,0,0},{0,0,0,0}}};
    #pragma unroll
    for (int mt=0; mt<2; mt++){
      #pragma unroll
      for (int ks=0; ks<4; ks++){
        bf16x8 a = *(const bf16x8*)(rb + ((size_t)(nt*32 + mt*16 + am))*RANK_ + ks*32 + aq*8);
        acc[mt][0] = __builtin_amdgcn_mfma_f32_16x16x32_bf16(a, bfr[0][ks], acc[mt][0], 0,0,0);
        acc[mt][1] = __builtin_amdgcn_mfma_f32_16x16x32_bf16(a, bfr[1][ks], acc[mt][1], 0,0,0);
      }
    }
    #pragma unroll
    for (int mt=0; mt<2; mt++){
      #pragma unroll
      for (int rg=0; rg<4; rg++){
        int row = mt*16 + aq*4 + rg;
        int n = nt*32 + row;
        int lbl = tok[row*T_ + nt + 1];
        float v0 = acc[mt][0][rg], v1 = acc[mt][1][rg];
        if (vb + am == lbl)      lablog[n] = v0;
        if (vb + 16 + am == lbl) lablog[n] = v1;
        float m = fmaxf(v0, v1);
        #pragma unroll
        for (int off=1; off<16; off<<=1) m = fmaxf(m, __shfl_xor(m, off));
        float l = expf(v0 - m) + expf(v1 - m);
        #pragma unroll
        for (int off=1; off<16; off<<=1) l += __shfl_xor(l, off);
        if (am == 0){ redM[w][row] = m; redL[w][row] = l; }
      }
    }
    __syncthreads();
    if (tid < 32){
      float M = fmaxf(fmaxf(redM[0][tid], redM[1][tid]), fmaxf(redM[2][tid], redM[3][tid]));
      float L = 0.f;
      #pragma unroll
      for (int ww=0; ww<4; ww++) L += redL[ww][tid]*expf(redM[ww][tid] - M);
      mpart[(size_t)(nt*32 + tid)*250 + vc] = M;
      lpart[(size_t)(nt*32 + tid)*250 + vc] = L;
    }
    __syncthreads();
  }
}

// ---------------- loss stage 1 ----------------
__global__ void k_loss1(const float* __restrict__ mpart, const float* __restrict__ lpart,
                        const float* __restrict__ lablog, const int* __restrict__ tgt_lens,
                        float* __restrict__ tpart){
  int t = blockIdx.x, tid = threadIdx.x;
  int row = tid >> 3, cq = tid & 7;
  int n = t*32 + row;
  float m = -1e30f;
  for (int c = cq; c < 250; c += 8) m = fmaxf(m, mpart[(size_t)n*250 + c]);
  #pragma unroll
  for (int off=1; off<8; off<<=1) m = fmaxf(m, __shfl_xor(m, off));
  float l = 0.f;
  for (int c = cq; c < 250; c += 8) l += lpart[(size_t)n*250 + c]*expf(mpart[(size_t)n*250 + c] - m);
  #pragma unroll
  for (int off=1; off<8; off<<=1) l += __shfl_xor(l, off);
  __shared__ float red[32];
  if (cq == 0)
    red[row] = (t < tgt_lens[row] - 1) ? (m + logf(l) - lablog[n]) : 0.f;
  __syncthreads();
  if (tid == 0){
    float s = 0.f;
    #pragma unroll
    for (int i=0;i<32;i++) s += red[i];
    tpart[t] = s;
  }
}

// ---------------- loss stage 2 ----------------
__global__ void k_loss2(const float* __restrict__ tpart, float* __restrict__ out){
  int tid = threadIdx.x;
  float v = (tid < TS) ? tpart[tid] : 0.f;
  #pragma unroll
  for (int off=32; off>0; off>>=1) v += __shfl_down(v, off);
  if (tid == 0) out[0] = v;
}

extern "C" void kernel_launch(void* const* d_in, const int* in_sizes, int n_in,
                              void* d_out, int out_size, void* d_ws, size_t ws_size,
                              hipStream_t stream){
  const float* enc      = (const float*)d_in[0];
  const float* es       = (const float*)d_in[1];
  const int*   tok      = (const int*)  d_in[2];
  const int*   enc_lens = (const int*)  d_in[3];
  const int*   tgt_lens = (const int*)  d_in[4];
  const float* E        = (const float*)d_in[5];
  const float* P        = (const float*)d_in[6];
  const float* W0       = (const float*)d_in[7];
  const float* U0       = (const float*)d_in[8];
  const float* b0       = (const float*)d_in[9];
  const float* W1       = (const float*)d_in[10];
  const float* U1       = (const float*)d_in[11];
  const float* b1       = (const float*)d_in[12];
  const float* Wo       = (const float*)d_in[13];
  const float* bo       = (const float*)d_in[14];
  float* out = (float*)d_out;

  float* fb = (float*)d_ws;
  size_t fo = 0;
  unsigned* bars = (unsigned*)(fb + fo); fo += 1024;
  float* pbuf0 = fb + fo; fo += (size_t)(TS+1)*2048;      // p_att slots [-1..46]
  float* mpart = fb + fo; fo += (size_t)TS*32*250;
  float* lpart = fb + fo; fo += (size_t)TS*32*250;
  float* lab   = fb + fo; fo += (size_t)TS*32;
  float* tpart = fb + fo; fo += 64;
  __bf16* bb = (__bf16*)(fb + fo);
  size_t bo2 = 0;
  __bf16* WP0    = bb + bo2; bo2 += (size_t)256*48*512;   // 6.29M  (alias: Eb post-loop)
  __bf16* WP1    = bb + bo2; bo2 += (size_t)256*64*512;   // 8.39M  (alias: WoP+PP post-loop)
  __bf16* encb   = bb + bo2; bo2 += (size_t)S_*32*C_;
  __bf16* embb   = bb + bo2; bo2 += (size_t)TS*32*EMB_;
  __bf16* featsb0= bb + bo2; bo2 += (size_t)(TS+1)*32*2048;
  __bf16* h0b0   = bb + bo2; bo2 += (size_t)(TS+1)*32*1024;
  __bf16* encWp  = bb + bo2; bo2 += (size_t)256*32*16*56; // 7.34M
  __bf16* rbuf   = bb + bo2; bo2 += (size_t)TS*32*RANK_;
  __bf16* hpb    = bb + bo2; bo2 += (size_t)TS*32*EMB_;
  __bf16* Eb     = WP0;                                    // alias (post-loop)
  __bf16* WoP    = WP1;                                    // alias (post-loop)
  __bf16* PP     = WP1 + (size_t)2048*512;                 // alias (post-loop)

  __bf16* featsb = featsb0 + (size_t)32*2048;
  __bf16* h0b    = h0b0 + (size_t)32*1024;

  k_init<<<128, 256, 0, stream>>>(es, h0b0, featsb0, pbuf0, bars);
  k_cvt<<<(S_*32*C_/4 + 255)/256, 256, 0, stream>>>(enc, encb, S_*32*C_);
  k_embed<<<TS*32, 128, 0, stream>>>(E, P, tok, embb);
  k_pack2<<<dim3(16,16), 256, 0, stream>>>(W0, 512,  W0, WP0, 48, 0);   // emb rows
  k_pack2<<<dim3(32,16), 256, 0, stream>>>(U0, 1024, U0, WP0, 48, 16);  // h0 rows
  k_pack2<<<dim3(64,16), 256, 0, stream>>>(W1, 1024, U1, WP1, 64, 0);
  k_encw<<<dim3(14,32), 256, 0, stream>>>(W0, encb, encWp);

  k_loop<<<NBLK, 512, 0, stream>>>(WP0, WP1, b0, b1, h0b, featsb,
                                   embb, encb, enc_lens, encWp, pbuf0, bars);

  k_cvt<<<(VOCAB_*RANK_/4 + 255)/256, 256, 0, stream>>>(E, Eb, VOCAB_*RANK_);
  k_packB<<<dim3(64,32), 64, 0, stream>>>(Wo, WoP, 2048, 512, 0);
  k_packB<<<dim3(16,8), 64, 0, stream>>>(P, PP, 512, 128, 1);
  k_ctx<<<32, 256, 0, stream>>>(encb, pbuf0, featsb);

  k_hproj_mfma<<<dim3(TS,16), 256, 0, stream>>>(featsb, WoP, bo, hpb);
  k_rproj_mfma<<<dim3(TS,4), 256, 0, stream>>>(hpb, PP, rbuf);
  k_vocab2<<<250, 256, 0, stream>>>(rbuf, Eb, tok, mpart, lpart, lab);
  k_loss1<<<TS, 256, 0, stream>>>(mpart, lpart, lab, tgt_lens, tpart);
  k_loss2<<<1, 64, 0, stream>>>(tpart, out);
}

// Round 6
// 1426.423 us; speedup vs baseline: 1.2702x; 1.2702x over previous
//
#include <hip/hip_runtime.h>
#include <math.h>

#define S_   56
#define B_   32
#define C_   1024
#define T_   48
#define TS   47
#define H_   1024
#define EMB_ 512
#define RANK_ 128
#define VOCAB_ 32000
#define G4   4096
#define NBLK 256

// flag-array barrier layout (unsigned words)
#define FL_DONE 8192
#define FL_P    8224
#define FL_PD   9248
#define FL_SIZE 10240

using bf16x8 = __attribute__((ext_vector_type(8))) __bf16;
using f32x4  = __attribute__((ext_vector_type(4))) float;

__device__ __forceinline__ float sigmoidf_(float x){ return 1.0f/(1.0f+expf(-x)); }
__device__ __forceinline__ float b2f(__bf16 x){ return (float)x; }
__device__ __forceinline__ f32x4 z4(){ f32x4 z = {0.f,0.f,0.f,0.f}; return z; }

// ---------- device-coherent (MALL write-through) store helpers ----------
#define AG __HIP_MEMORY_SCOPE_AGENT
__device__ __forceinline__ void stc_u64(void* p, unsigned long long v){
  __hip_atomic_store((unsigned long long*)p, v, __ATOMIC_RELAXED, AG);
}
__device__ __forceinline__ void stc_bf16(__bf16* p, __bf16 v){
  union { __bf16 b; unsigned short s; } t; t.b = v;
  __hip_atomic_store((unsigned short*)p, t.s, __ATOMIC_RELAXED, AG);
}

// ---------------- shared-memory structures for the persistent kernel ----------------
struct RedShared {
  float red[4][2][16][18];    // [wavepair][mtile][row][col(+pad)]
};
struct AttnShared {
  union { float hS[1024]; float cred[3][128][8]; } u;  // hS dead before cred written
  float sS[64];
  float pS[64];
};
union alignas(16) SharedU { RedShared r; AttnShared a; };

// ---------------- flag-array grid barrier: parallel arrive, single observer ----------------
__device__ __forceinline__ void bar_arrive(unsigned* bars, int bi, unsigned e){
  asm volatile("s_waitcnt vmcnt(0)" ::: "memory");
  __syncthreads();
  if (threadIdx.x == 0)
    __hip_atomic_store(bars + (size_t)bi*32, e, __ATOMIC_RELAXED, AG);
}
__device__ __forceinline__ void bar_wait(unsigned* bars, int bi, unsigned e){
  if (bi == 0){
    if (threadIdx.x < 256){
      while (__hip_atomic_load(bars + (size_t)threadIdx.x*32, __ATOMIC_RELAXED, AG) < e)
        __builtin_amdgcn_s_sleep(1);
    }
    __syncthreads();
    if (threadIdx.x == 0)
      __hip_atomic_store(bars + FL_DONE, e, __ATOMIC_RELAXED, AG);
  } else {
    if (threadIdx.x == 0){
      while (__hip_atomic_load(bars + FL_DONE, __ATOMIC_RELAXED, AG) < e)
        __builtin_amdgcn_s_sleep(1);
    }
    __syncthreads();
  }
  asm volatile("" ::: "memory");
}
// ctx-ready wait: 32 producer flags, block 0 aggregates into pdone
__device__ __forceinline__ void pflag_wait(unsigned* bars, int bi, unsigned t){
  if (bi == 0){
    if (threadIdx.x < 32){
      while (__hip_atomic_load(bars + FL_P + (size_t)threadIdx.x*32, __ATOMIC_RELAXED, AG) < t)
        __builtin_amdgcn_s_sleep(1);
    }
    __syncthreads();
    if (threadIdx.x == 0)
      __hip_atomic_store(bars + FL_PD, t, __ATOMIC_RELAXED, AG);
  } else {
    if (threadIdx.x == 0){
      while (__hip_atomic_load(bars + FL_PD, __ATOMIC_RELAXED, AG) < t)
        __builtin_amdgcn_s_sleep(1);
    }
    __syncthreads();
  }
  asm volatile("" ::: "memory");
}

// ---------------- init ----------------
// h0bm1: h0[-1] slot (32x1024). fm1: feats[-1] slot (32x2048): h1_init @0, ctx0=0 @1024.
__global__ void k_init(const float* __restrict__ es, __bf16* h0bm1, __bf16* fm1,
                       unsigned* bars){
  int i = blockIdx.x*blockDim.x + threadIdx.x;
  if (i < 32*H_){
    int b = i >> 10, j = i & 1023;
    h0bm1[(size_t)b*1024 + j]       = (__bf16)es[i];           // h0 <- es[0]
    fm1[(size_t)b*2048 + j]         = (__bf16)es[32*H_ + i];   // h1 <- es[1]
    fm1[(size_t)b*2048 + 1024 + j]  = (__bf16)0.0f;            // ctx0 = 0
  }
  if (i < FL_SIZE) bars[i] = 0u;
}

// ---------------- fp32 -> bf16 ----------------
__global__ void k_cvt(const float* __restrict__ src, __bf16* __restrict__ dst, int n){
  int i = (blockIdx.x*blockDim.x + threadIdx.x)*4;
  if (i < n){
    float4 v = *(const float4*)(src + i);
    dst[i+0]=(__bf16)v.x; dst[i+1]=(__bf16)v.y; dst[i+2]=(__bf16)v.z; dst[i+3]=(__bf16)v.w;
  }
}

// ---------------- embedding ----------------
__global__ void k_embed(const float* __restrict__ E, const float* __restrict__ P,
                        const int* __restrict__ tok, __bf16* __restrict__ embb){
  int blk = blockIdx.x;            // t*32+b
  int t = blk >> 5, b = blk & 31, tid = threadIdx.x;   // 128 threads
  __shared__ float er[RANK_];
  int tk = tok[b*T_ + t];
  er[tid] = E[(size_t)tk*RANK_ + tid];
  __syncthreads();
  float4 acc = {0.f,0.f,0.f,0.f};
  int e = tid*4;
  for (int r2 = 0; r2 < RANK_; r2++){
    float ev = er[r2];
    float4 p = *(const float4*)(P + (size_t)r2*EMB_ + e);
    acc.x += ev*p.x; acc.y += ev*p.y; acc.z += ev*p.z; acc.w += ev*p.w;
  }
  size_t o = (size_t)blk*EMB_ + e;
  embb[o+0]=(__bf16)acc.x; embb[o+1]=(__bf16)acc.y;
  embb[o+2]=(__bf16)acc.z; embb[o+3]=(__bf16)acc.w;
}

// ---------------- pack [W;U] into per-block LDS-resident frag order ----------------
__global__ void k_pack2(const float* __restrict__ W, int K1, const float* __restrict__ U,
                        __bf16* __restrict__ dst, int NCH){
  int ch = blockIdx.x;            // k-chunk (32 rows)
  int g  = blockIdx.y >> 2;       // gate 0..3
  int band = blockIdx.y & 3;      // 256-col band within the gate
  int tid = threadIdx.x;          // 256 threads
  __shared__ __bf16 Tl[32][264];
  {
    int r = tid>>3, cs = tid&7;   // row, col-octet (32 cols each)
    int kk = ch*32 + r;
    const float* src = (kk < K1) ? (W + (size_t)kk*G4 + g*1024 + band*256 + cs*32)
                                 : (U + (size_t)(kk-K1)*G4 + g*1024 + band*256 + cs*32);
    #pragma unroll
    for (int u=0;u<8;u++){
      float4 v = *(const float4*)(src + u*4);
      Tl[r][cs*32+u*4+0]=(__bf16)v.x; Tl[r][cs*32+u*4+1]=(__bf16)v.y;
      Tl[r][cs*32+u*4+2]=(__bf16)v.z; Tl[r][cs*32+u*4+3]=(__bf16)v.w;
    }
  }
  __syncthreads();
  int bil = tid>>2, aq = tid&3;   // 64 local blocks x 4 k-quarters
  int bi = band*64 + bil;
  #pragma unroll
  for (int q=0;q<4;q++){
    __bf16 o8[8];
    #pragma unroll
    for (int i=0;i<8;i++) o8[i] = Tl[aq*8+i][bil*4+q];
    int lane = aq*16 + g*4 + q;
    *(bf16x8*)(dst + (((size_t)bi*NCH + ch)*64 + lane)*8) = *(bf16x8*)o8;
  }
}

// ---------------- generic B-frag pack (16x16x32) for Wo / P^T ----------------
__global__ void k_packB(const float* __restrict__ src, __bf16* __restrict__ dst,
                        int K, int N, int tr){
  int kk0 = blockIdx.x*32, j0 = blockIdx.y*16, lane = threadIdx.x;  // 64 threads
  int am = lane&15, aq = lane>>4;
  int j = j0 + am;
  __bf16 o8[8];
  #pragma unroll
  for (int i=0;i<8;i++){
    int k = kk0 + aq*8 + i;
    float v = tr ? src[(size_t)j*K + k] : src[(size_t)k*N + j];
    o8[i] = (__bf16)v;
  }
  int NCH = K/32, jt = j0>>4, ch = kk0>>5;
  *(bf16x8*)(dst + (((size_t)jt*NCH + ch)*64 + lane)*8) = *(bf16x8*)o8;
}

// ---------------- chunk accumulate: NC chunks of K=32 against LDS weights ----------------
template<int NC>
__device__ __forceinline__ void accum(f32x4& acc0, f32x4& acc1,
    const __bf16* __restrict__ abase, int rs, const __bf16* wlds,
    int ch0, int am, int aq, int lane)
{
  const __bf16* a0p = abase + (size_t)am*rs + aq*8;
  const __bf16* a1p = abase + (size_t)(am+16)*rs + aq*8;
  const __bf16* wl  = wlds + (size_t)lane*8;
  #pragma unroll
  for (int c=0;c<NC;c++){
    int ch = ch0 + c;
    bf16x8 a0 = *(const bf16x8*)(a0p + (size_t)ch*32);
    bf16x8 a1 = *(const bf16x8*)(a1p + (size_t)ch*32);
    bf16x8 w  = *(const bf16x8*)(wl  + (size_t)ch*512);
    acc0 = __builtin_amdgcn_mfma_f32_16x16x32_bf16(a0, w, acc0, 0, 0, 0);
    acc1 = __builtin_amdgcn_mfma_f32_16x16x32_bf16(a1, w, acc1, 0, 0, 0);
  }
}

// ---------------- 8-wave reduce + LSTM cell (c-state in registers) ----------------
__device__ __forceinline__ void reduce_cell(SharedU& su, const f32x4& acc0, const f32x4& acc1,
    int bi, int tid, const float* __restrict__ bias, float& creg,
    __bf16* __restrict__ hout, int stride)
{
  int kw = tid>>6, lane = tid&63, am = lane&15, aq = lane>>4;
  if (kw >= 4){
    #pragma unroll
    for (int rg=0;rg<4;rg++){
      su.r.red[kw-4][0][aq*4+rg][am] = acc0[rg];
      su.r.red[kw-4][1][aq*4+rg][am] = acc1[rg];
    }
  }
  __syncthreads();
  if (kw < 4){
    #pragma unroll
    for (int rg=0;rg<4;rg++){
      su.r.red[kw][0][aq*4+rg][am] += acc0[rg];
      su.r.red[kw][1][aq*4+rg][am] += acc1[rg];
    }
  }
  __syncthreads();
  if (tid < 128){
    int b = tid>>2, q = tid&3;
    int mt = b>>4, r = b&15;
    float G0=0.f, G1=0.f, G2=0.f, G3=0.f;
    #pragma unroll
    for (int w2=0; w2<4; w2++){
      G0 += su.r.red[w2][mt][r][q];
      G1 += su.r.red[w2][mt][r][4+q];
      G2 += su.r.red[w2][mt][r][8+q];
      G3 += su.r.red[w2][mt][r][12+q];
    }
    int j = bi*4 + q;
    float gi = G0 + bias[j];
    float gf = G1 + bias[1024 + j];
    float gg = G2 + bias[2048 + j];
    float go = G3 + bias[3072 + j];
    float ii = sigmoidf_(gi), ff = sigmoidf_(gf), gv = tanhf(gg), oo = sigmoidf_(go);
    float cv = ff*creg + ii*gv;
    float hv = oo*tanhf(cv);
    creg = cv;
    stc_bf16(hout + (size_t)b*stride + j, (__bf16)hv);
  }
}

// ---------------- attention for one batch row (512 threads) ----------------
__device__ __forceinline__ void attn_block(AttnShared& sa, int b, int tid,
    const __bf16* __restrict__ encb, const int* __restrict__ enc_lens,
    __bf16* __restrict__ fbt)
{
  if (tid < 128){
    bf16x8 h8 = *(const bf16x8*)(fbt + (size_t)b*2048 + tid*8);
    #pragma unroll
    for (int u=0;u<8;u++) sa.u.hS[tid*8+u] = b2f(h8[u]);
  }
  __syncthreads();
  int w = tid >> 6, lane = tid & 63;
  for (int s = w; s < S_; s += 8){
    const __bf16* er = encb + ((size_t)s*32 + b)*C_;
    float a = 0.f;
    #pragma unroll
    for (int half = 0; half < 2; half++){
      int k = lane*8 + half*512;
      bf16x8 e8 = *(const bf16x8*)(er + k);
      #pragma unroll
      for (int u=0;u<8;u++) a += b2f(e8[u]) * sa.u.hS[k+u];
    }
    #pragma unroll
    for (int off=32; off>0; off>>=1) a += __shfl_down(a, off);
    if (lane == 0) sa.sS[s] = a;
  }
  __syncthreads();
  if (tid < 64){
    int len = enc_lens[b];
    float sc = (tid < len && tid < S_) ? sa.sS[tid] : -1e30f;
    float m = sc;
    #pragma unroll
    for (int off=32; off>0; off>>=1) m = fmaxf(m, __shfl_xor(m, off));
    float e = expf(sc - m);
    float ssum = e;
    #pragma unroll
    for (int off=32; off>0; off>>=1) ssum += __shfl_xor(ssum, off);
    sa.pS[tid] = e / ssum;
  }
  __syncthreads();                    // hS dead past here -> cred may overlay
  int cg = tid & 127, sg = tid >> 7;  // 4-way s-split
  float a8[8];
  #pragma unroll
  for (int i=0;i<8;i++) a8[i] = 0.f;
  for (int s = sg; s < S_; s += 4){
    float p = sa.pS[s];
    bf16x8 e8 = *(const bf16x8*)(encb + ((size_t)s*32 + b)*C_ + cg*8);
    #pragma unroll
    for (int i=0;i<8;i++) a8[i] += p * b2f(e8[i]);
  }
  if (sg > 0){
    #pragma unroll
    for (int i=0;i<8;i++) sa.u.cred[sg-1][cg][i] = a8[i];
  }
  __syncthreads();
  if (sg == 0){
    union { __bf16 bb[8]; unsigned long long u[2]; } cu;
    #pragma unroll
    for (int i=0;i<8;i++){
      float v = a8[i] + sa.u.cred[0][cg][i] + sa.u.cred[1][cg][i] + sa.u.cred[2][cg][i];
      cu.bb[i] = (__bf16)v;
    }
    stc_u64(fbt + (size_t)b*2048 + 1024 + cg*8,     cu.u[0]);
    stc_u64(fbt + (size_t)b*2048 + 1024 + cg*8 + 4, cu.u[1]);
  }
}

// ---------------- persistent decode loop (256 blocks x 512 threads) ----------------
// Append-only cross-block buffers (h0b[t], featsb[t]) -> plain cached loads stay fresh,
// no fences. 2 flag-array barriers/step + 1 flag-array ctx wait.
__global__ __launch_bounds__(512) void k_loop(
    const __bf16* __restrict__ WP0, const __bf16* __restrict__ WP1,
    const float* __restrict__ b0, const float* __restrict__ b1,
    __bf16* __restrict__ h0b,      // h0b[t] base (t=0 slot; t=-1 valid below)
    __bf16* __restrict__ featsb,   // featsb[t] base (t=-1 valid below)
    const __bf16* __restrict__ embb,
    const __bf16* __restrict__ encb, const int* __restrict__ enc_lens,
    unsigned* bars)
{
  __shared__ __bf16 wB0[80*512];   // 81920 B : gemm0 weight slice (N=16 gate-cols, K=2560)
  __shared__ __bf16 wB1[64*512];   // 65536 B : gemm1 weight slice (N=16, K=2048)
  __shared__ SharedU su;           // reduce / attention overlay
  int bi = blockIdx.x, tid = threadIdx.x;
  int kw = tid>>6, lane = tid&63, am = lane&15, aq = lane>>4;

  // one-time weight load into LDS
  {
    const bf16x8* g0 = (const bf16x8*)(WP0 + (size_t)bi*80*512);
    const bf16x8* g1 = (const bf16x8*)(WP1 + (size_t)bi*64*512);
    bf16x8* l0 = (bf16x8*)wB0;
    bf16x8* l1 = (bf16x8*)wB1;
    for (int idx = tid; idx < 80*64; idx += 512) l0[idx] = g0[idx];
    for (int idx = tid; idx < 64*64; idx += 512) l1[idx] = g1[idx];
  }
  __syncthreads();

  float c0r = 0.f, c1r = 0.f;
  f32x4 g00 = z4(), g01 = z4(), g10 = z4(), g11 = z4();

  // prologue: gates0(t=0) partial = emb_0 @ W0e + h0_init @ U0
  accum<2>(g00, g01, embb,                 512,  wB0, kw*2,    am, aq, lane);
  accum<4>(g00, g01, h0b - 32768 - 1536,   1024, wB0, 48+kw*4, am, aq, lane);

  unsigned e = 0;
  for (int t = 0; t < TS; t++){
    const __bf16* fprev = featsb + ((size_t)(t-1))*65536;  // [h1_{t-1}(1024), ctx_t(1024)]
    __bf16* h0t = h0b + (size_t)t*32768;
    __bf16* ft  = featsb + (size_t)t*65536;

    // ---- phase 1: + ctx part -> gates0 -> cell0 -> h0_t ----
    pflag_wait(bars, bi, (unsigned)t);
    accum<4>(g00, g01, fprev + 512, 2048, wB0, 16+kw*4, am, aq, lane);
    reduce_cell(su, g00, g01, bi, tid, b0, c0r, h0t, 1024);
    g00 = z4(); g01 = z4();
    bar_arrive(bars, bi, ++e);
    // spin-work: gates1 partial U1 @ h1_{t-1}
    accum<4>(g10, g11, fprev - 1024, 2048, wB1, 32+kw*4, am, aq, lane);
    bar_wait(bars, bi, e);

    // ---- phase 2: + W1 @ h0_t -> gates1 -> cell1 -> h1_t ----
    accum<4>(g10, g11, h0t, 1024, wB1, kw*4, am, aq, lane);
    reduce_cell(su, g10, g11, bi, tid, b1, c1r, ft, 2048);
    g10 = z4(); g11 = z4();
    bar_arrive(bars, bi, ++e);
    // spin-work: gates0(t+1) partial = emb_{t+1} @ W0 + h0_t @ U0
    if (t + 1 < TS){
      accum<2>(g00, g01, embb + (size_t)(t+1)*16384, 512,  wB0, kw*2,    am, aq, lane);
      accum<4>(g00, g01, h0t - 1536,                 1024, wB0, 48+kw*4, am, aq, lane);
    }
    bar_wait(bars, bi, e);

    // ---- phase 3: attention (32 blocks) -> ctx_{t+1} + per-block flag ----
    if (bi < 32){
      attn_block(su.a, bi, tid, encb, enc_lens, ft);
      asm volatile("s_waitcnt vmcnt(0)" ::: "memory");
      __syncthreads();
      if (tid == 0)
        __hip_atomic_store(bars + FL_P + (size_t)bi*32, (unsigned)(t+1), __ATOMIC_RELAXED, AG);
    }
  }
}

// ---------------- hproj = tanh(featsb @ WoP + bo) -> hpb (bf16 MFMA) ----------------
__global__ __launch_bounds__(256) void k_hproj_mfma(
    const __bf16* __restrict__ fb, const __bf16* __restrict__ WoP,
    const float* __restrict__ bo, __bf16* __restrict__ hpb)
{
  int nt = blockIdx.x, jb = blockIdx.y, tid = threadIdx.x;  // (47,16)
  int w = tid>>6, lane = tid&63;
  int mt = w&1, jw = w>>1;
  int am = lane&15, aq = lane>>4;
  const __bf16* aRow = fb + ((size_t)(nt*32 + mt*16 + am))*2048 + aq*8;
  int jt = jb*2 + jw;
  const __bf16* bptr = WoP + ((size_t)jt*64)*512 + lane*8;
  f32x4 acc = {0,0,0,0};
  bf16x8 ar0 = *(const bf16x8*)(aRow);
  bf16x8 br0 = *(const bf16x8*)(bptr);
  bf16x8 ar1 = *(const bf16x8*)(aRow + 32);
  bf16x8 br1 = *(const bf16x8*)(bptr + 512);
  for (int ch = 0; ch < 64; ch += 2){
    bf16x8 a0 = ar0, b0 = br0, a1 = ar1, b1 = br1;
    if (ch + 2 < 64){
      ar0 = *(const bf16x8*)(aRow + (ch+2)*32);
      br0 = *(const bf16x8*)(bptr + (size_t)(ch+2)*512);
      ar1 = *(const bf16x8*)(aRow + (ch+3)*32);
      br1 = *(const bf16x8*)(bptr + (size_t)(ch+3)*512);
    }
    acc = __builtin_amdgcn_mfma_f32_16x16x32_bf16(a0, b0, acc, 0, 0, 0);
    acc = __builtin_amdgcn_mfma_f32_16x16x32_bf16(a1, b1, acc, 0, 0, 0);
  }
  int jcol = jb*32 + jw*16 + am;
  float bv = bo[jcol];
  #pragma unroll
  for (int rg=0; rg<4; rg++){
    int m = nt*32 + mt*16 + aq*4 + rg;
    hpb[(size_t)m*512 + jcol] = (__bf16)tanhf(acc[rg] + bv);
  }
}

// ---------------- r = hpb @ P^T -> rbuf (bf16 MFMA) ----------------
__global__ __launch_bounds__(256) void k_rproj_mfma(
    const __bf16* __restrict__ hpb, const __bf16* __restrict__ PP,
    __bf16* __restrict__ rb)
{
  int nt = blockIdx.x, jb = blockIdx.y, tid = threadIdx.x;  // (47,4)
  int w = tid>>6, lane = tid&63;
  int mt = w&1, jw = w>>1;
  int am = lane&15, aq = lane>>4;
  const __bf16* aRow = hpb + ((size_t)(nt*32 + mt*16 + am))*512 + aq*8;
  int jt = jb*2 + jw;
  const __bf16* bptr = PP + ((size_t)jt*16)*512 + lane*8;
  f32x4 acc = {0,0,0,0};
  #pragma unroll
  for (int ch = 0; ch < 16; ch++){
    bf16x8 a = *(const bf16x8*)(aRow + ch*32);
    bf16x8 b = *(const bf16x8*)(bptr + (size_t)ch*512);
    acc = __builtin_amdgcn_mfma_f32_16x16x32_bf16(a, b, acc, 0, 0, 0);
  }
  int jcol = jb*32 + jw*16 + am;
  #pragma unroll
  for (int rg=0; rg<4; rg++){
    int m = nt*32 + mt*16 + aq*4 + rg;
    rb[(size_t)m*RANK_ + jcol] = (__bf16)acc[rg];
  }
}

// ---------------- vocab GEMM: grid 250 v-chunks, loop all 47 n-tiles ----------------
__global__ __launch_bounds__(256) void k_vocab2(
    const __bf16* __restrict__ rb, const __bf16* __restrict__ Eb,
    const int* __restrict__ tok,
    float* __restrict__ mpart, float* __restrict__ lpart,
    float* __restrict__ lablog)
{
  int vc = blockIdx.x, tid = threadIdx.x;
  int w = tid>>6, lane = tid&63;
  int am = lane&15, aq = lane>>4;
  int vb = vc*128 + w*32;
  bf16x8 bfr[2][4];
  #pragma unroll
  for (int vt=0; vt<2; vt++)
    #pragma unroll
    for (int ks=0; ks<4; ks++)
      bfr[vt][ks] = *(const bf16x8*)(Eb + ((size_t)(vb + vt*16 + am))*RANK_ + ks*32 + aq*8);

  __shared__ float redM[4][32], redL[4][32];
  for (int nt = 0; nt < TS; nt++){
    f32x4 acc[2][2] = {{{0,0,0,0},{0,0,0,0}},{{0,0,0,0},{0,0,0,0}}};
    #pragma unroll
    for (int mt=0; mt<2; mt++){
      #pragma unroll
      for (int ks=0; ks<4; ks++){
        bf16x8 a = *(const bf16x8*)(rb + ((size_t)(nt*32 + mt*16 + am))*RANK_ + ks*32 + aq*8);
        acc[mt][0] = __builtin_amdgcn_mfma_f32_16x16x32_bf16(a, bfr[0][ks], acc[mt][0], 0,0,0);
        acc[mt][1] = __builtin_amdgcn_mfma_f32_16x16x32_bf16(a, bfr[1][ks], acc[mt][1], 0,0,0);
      }
    }
    #pragma unroll
    for (int mt=0; mt<2; mt++){
      #pragma unroll
      for (int rg=0; rg<4; rg++){
        int row = mt*16 + aq*4 + rg;
        int n = nt*32 + row;
        int lbl = tok[row*T_ + nt + 1];
        float v0 = acc[mt][0][rg], v1 = acc[mt][1][rg];
        if (vb + am == lbl)      lablog[n] = v0;
        if (vb + 16 + am == lbl) lablog[n] = v1;
        float m = fmaxf(v0, v1);
        #pragma unroll
        for (int off=1; off<16; off<<=1) m = fmaxf(m, __shfl_xor(m, off));
        float l = expf(v0 - m) + expf(v1 - m);
        #pragma unroll
        for (int off=1; off<16; off<<=1) l += __shfl_xor(l, off);
        if (am == 0){ redM[w][row] = m; redL[w][row] = l; }
      }
    }
    __syncthreads();
    if (tid < 32){
      float M = fmaxf(fmaxf(redM[0][tid], redM[1][tid]), fmaxf(redM[2][tid], redM[3][tid]));
      float L = 0.f;
      #pragma unroll
      for (int ww=0; ww<4; ww++) L += redL[ww][tid]*expf(redM[ww][tid] - M);
      mpart[(size_t)(nt*32 + tid)*250 + vc] = M;
      lpart[(size_t)(nt*32 + tid)*250 + vc] = L;
    }
    __syncthreads();
  }
}

// ---------------- loss stage 1 ----------------
__global__ void k_loss1(const float* __restrict__ mpart, const float* __restrict__ lpart,
                        const float* __restrict__ lablog, const int* __restrict__ tgt_lens,
                        float* __restrict__ tpart){
  int t = blockIdx.x, tid = threadIdx.x;
  int row = tid >> 3, cq = tid & 7;
  int n = t*32 + row;
  float m = -1e30f;
  for (int c = cq; c < 250; c += 8) m = fmaxf(m, mpart[(size_t)n*250 + c]);
  #pragma unroll
  for (int off=1; off<8; off<<=1) m = fmaxf(m, __shfl_xor(m, off));
  float l = 0.f;
  for (int c = cq; c < 250; c += 8) l += lpart[(size_t)n*250 + c]*expf(mpart[(size_t)n*250 + c] - m);
  #pragma unroll
  for (int off=1; off<8; off<<=1) l += __shfl_xor(l, off);
  __shared__ float red[32];
  if (cq == 0)
    red[row] = (t < tgt_lens[row] - 1) ? (m + logf(l) - lablog[n]) : 0.f;
  __syncthreads();
  if (tid == 0){
    float s = 0.f;
    #pragma unroll
    for (int i=0;i<32;i++) s += red[i];
    tpart[t] = s;
  }
}

// ---------------- loss stage 2 ----------------
__global__ void k_loss2(const float* __restrict__ tpart, float* __restrict__ out){
  int tid = threadIdx.x;
  float v = (tid < TS) ? tpart[tid] : 0.f;
  #pragma unroll
  for (int off=32; off>0; off>>=1) v += __shfl_down(v, off);
  if (tid == 0) out[0] = v;
}

extern "C" void kernel_launch(void* const* d_in, const int* in_sizes, int n_in,
                              void* d_out, int out_size, void* d_ws, size_t ws_size,
                              hipStream_t stream){
  const float* enc      = (const float*)d_in[0];
  const float* es       = (const float*)d_in[1];
  const int*   tok      = (const int*)  d_in[2];
  const int*   enc_lens = (const int*)  d_in[3];
  const int*   tgt_lens = (const int*)  d_in[4];
  const float* E        = (const float*)d_in[5];
  const float* P        = (const float*)d_in[6];
  const float* W0       = (const float*)d_in[7];
  const float* U0       = (const float*)d_in[8];
  const float* b0       = (const float*)d_in[9];
  const float* W1       = (const float*)d_in[10];
  const float* U1       = (const float*)d_in[11];
  const float* b1       = (const float*)d_in[12];
  const float* Wo       = (const float*)d_in[13];
  const float* bo       = (const float*)d_in[14];
  float* out = (float*)d_out;

  float* fb = (float*)d_ws;
  size_t fo = 0;
  float* mpart = fb + fo; fo += (size_t)TS*32*250;
  float* lpart = fb + fo; fo += (size_t)TS*32*250;
  float* lab   = fb + fo; fo += (size_t)TS*32;
  float* tpart = fb + fo; fo += 64;
  unsigned* bars = (unsigned*)(fb + fo); fo += FL_SIZE;
  __bf16* bb = (__bf16*)(fb + fo);
  size_t bo2 = 0;
  __bf16* WP0    = bb + bo2; bo2 += (size_t)4096*2560;   // dead after k_loop's LDS load
  __bf16* WP1    = bb + bo2; bo2 += (size_t)4096*2048;
  __bf16* encb   = bb + bo2; bo2 += (size_t)S_*32*C_;
  __bf16* embb   = bb + bo2; bo2 += (size_t)TS*32*EMB_;
  __bf16* rbuf   = bb + bo2; bo2 += (size_t)TS*32*RANK_;
  __bf16* WoP    = bb + bo2; bo2 += (size_t)2048*512;
  __bf16* PP     = bb + bo2; bo2 += (size_t)512*128;
  __bf16* featsb0= bb + bo2; bo2 += (size_t)(TS+1)*32*2048;   // slot -1 + 47 steps
  __bf16* hpb    = bb + bo2; bo2 += (size_t)TS*32*EMB_;
  __bf16* h0b0   = bb + bo2; bo2 += (size_t)(TS+1)*32*1024;   // slot -1 + 47 steps
  __bf16* Eb     = WP0;      // ALIAS: converted after k_loop (WP0 dead), used by k_vocab2

  __bf16* featsb = featsb0 + (size_t)32*2048;   // featsb[t], t>=0; [-1] = featsb0
  __bf16* h0b    = h0b0 + (size_t)32*1024;

  k_init<<<128, 256, 0, stream>>>(es, h0b0, featsb0, bars);
  k_cvt<<<(S_*32*C_/4 + 255)/256, 256, 0, stream>>>(enc, encb, S_*32*C_);
  k_embed<<<TS*32, 128, 0, stream>>>(E, P, tok, embb);
  k_pack2<<<dim3(80,16), 256, 0, stream>>>(W0, 1536, U0, WP0, 80);
  k_pack2<<<dim3(64,16), 256, 0, stream>>>(W1, 1024, U1, WP1, 64);
  k_packB<<<dim3(64,32), 64, 0, stream>>>(Wo, WoP, 2048, 512, 0);
  k_packB<<<dim3(16,8), 64, 0, stream>>>(P, PP, 512, 128, 1);

  k_loop<<<NBLK, 512, 0, stream>>>(WP0, WP1, b0, b1, h0b, featsb,
                                   embb, encb, enc_lens, bars);

  // E -> bf16 AFTER k_loop (Eb aliases WP0, which is dead past the LDS weight load)
  k_cvt<<<(VOCAB_*RANK_/4 + 255)/256, 256, 0, stream>>>(E, Eb, VOCAB_*RANK_);

  k_hproj_mfma<<<dim3(TS,16), 256, 0, stream>>>(featsb, WoP, bo, hpb);
  k_rproj_mfma<<<dim3(TS,4), 256, 0, stream>>>(hpb, PP, rbuf);
  k_vocab2<<<250, 256, 0, stream>>>(rbuf, Eb, tok, mpart, lpart, lab);
  k_loss1<<<TS, 256, 0, stream>>>(mpart, lpart, lab, tgt_lens, tpart);
  k_loss2<<<1, 64, 0, stream>>>(tpart, out);
}

// Round 7
// 1392.426 us; speedup vs baseline: 1.3012x; 1.0244x over previous
//
#include <hip/hip_runtime.h>
#include <math.h>

#define S_   56
#define B_   32
#define C_   1024
#define T_   48
#define TS   47
#define H_   1024
#define EMB_ 512
#define RANK_ 128
#define VOCAB_ 32000
#define G4   4096
#define NBLK 256

// flag-array barrier layout (unsigned words, 128B-strided flags)
#define FL_DONE 8192
#define FL_P    8224
#define FL_SIZE 10496

using bf16x8 = __attribute__((ext_vector_type(8))) __bf16;
using f32x4  = __attribute__((ext_vector_type(4))) float;

__device__ __forceinline__ float sigmoidf_(float x){ return 1.0f/(1.0f+expf(-x)); }
__device__ __forceinline__ float b2f(__bf16 x){ return (float)x; }
__device__ __forceinline__ f32x4 z4(){ f32x4 z = {0.f,0.f,0.f,0.f}; return z; }

// ---------- device-coherent (MALL write-through) store helpers ----------
#define AG __HIP_MEMORY_SCOPE_AGENT
__device__ __forceinline__ void stc_u64(void* p, unsigned long long v){
  __hip_atomic_store((unsigned long long*)p, v, __ATOMIC_RELAXED, AG);
}

// ---------------- shared-memory structures for the persistent kernel ----------------
struct RedShared {
  float red[4][2][16][18];    // [wavepair][mtile][row][col(+pad)]
};
struct AttnShared {
  union { float hS[1024]; float cred[7][64][8]; } u;  // hS dead before cred written
  float sS[64];
  float pS[64];
};
union alignas(16) SharedU { RedShared r; AttnShared a; };

// ---------------- flag-array grid sync primitives ----------------
__device__ __forceinline__ void bar_arrive(unsigned* bars, int bi, unsigned e){
  asm volatile("s_waitcnt vmcnt(0)" ::: "memory");
  __syncthreads();
  if (threadIdx.x == 0)
    __hip_atomic_store(bars + (size_t)bi*32, e, __ATOMIC_RELAXED, AG);
}
// full barrier, observer = block 255 publishes FL_DONE, others poll it
__device__ __forceinline__ void bar_wait_all(unsigned* bars, int bi, unsigned e){
  if (bi == 255){
    if (threadIdx.x < 256){
      while (__hip_atomic_load(bars + (size_t)threadIdx.x*32, __ATOMIC_RELAXED, AG) < e) {}
    }
    __syncthreads();
    if (threadIdx.x == 0)
      __hip_atomic_store(bars + FL_DONE, e, __ATOMIC_RELAXED, AG);
  } else {
    if (threadIdx.x == 0){
      while (__hip_atomic_load(bars + FL_DONE, __ATOMIC_RELAXED, AG) < e) {}
    }
    __syncthreads();
  }
  asm volatile("" ::: "memory");
}
// direct-poll wait on all 256 arrive flags (used by the 64 attn blocks only)
__device__ __forceinline__ void bar_wait_direct(unsigned* bars, unsigned e){
  if (threadIdx.x < 256){
    while (__hip_atomic_load(bars + (size_t)threadIdx.x*32, __ATOMIC_RELAXED, AG) < e) {}
  }
  __syncthreads();
  asm volatile("" ::: "memory");
}
// direct-poll on the 64 attn producer flags (all blocks)
__device__ __forceinline__ void pflag_wait(unsigned* bars, unsigned t){
  if (threadIdx.x < 64){
    while (__hip_atomic_load(bars + FL_P + (size_t)threadIdx.x*32, __ATOMIC_RELAXED, AG) < t)
      __builtin_amdgcn_s_sleep(2);
  }
  __syncthreads();
  asm volatile("" ::: "memory");
}

// ---------------- init ----------------
// h0bm1: h0[-1] slot (32x1024). fm1: feats[-1] slot (32x2048): h1_init @0, ctx0=0 @1024.
__global__ void k_init(const float* __restrict__ es, __bf16* h0bm1, __bf16* fm1,
                       unsigned* bars){
  int i = blockIdx.x*blockDim.x + threadIdx.x;
  if (i < 32*H_){
    int b = i >> 10, j = i & 1023;
    h0bm1[(size_t)b*1024 + j]       = (__bf16)es[i];           // h0 <- es[0]
    fm1[(size_t)b*2048 + j]         = (__bf16)es[32*H_ + i];   // h1 <- es[1]
    fm1[(size_t)b*2048 + 1024 + j]  = (__bf16)0.0f;            // ctx0 = 0
  }
  if (i < FL_SIZE) bars[i] = 0u;
}

// ---------------- fp32 -> bf16 ----------------
__global__ void k_cvt(const float* __restrict__ src, __bf16* __restrict__ dst, int n){
  int i = (blockIdx.x*blockDim.x + threadIdx.x)*4;
  if (i < n){
    float4 v = *(const float4*)(src + i);
    dst[i+0]=(__bf16)v.x; dst[i+1]=(__bf16)v.y; dst[i+2]=(__bf16)v.z; dst[i+3]=(__bf16)v.w;
  }
}

// ---------------- embedding ----------------
__global__ void k_embed(const float* __restrict__ E, const float* __restrict__ P,
                        const int* __restrict__ tok, __bf16* __restrict__ embb){
  int blk = blockIdx.x;            // t*32+b
  int t = blk >> 5, b = blk & 31, tid = threadIdx.x;   // 128 threads
  __shared__ float er[RANK_];
  int tk = tok[b*T_ + t];
  er[tid] = E[(size_t)tk*RANK_ + tid];
  __syncthreads();
  float4 acc = {0.f,0.f,0.f,0.f};
  int e = tid*4;
  for (int r2 = 0; r2 < RANK_; r2++){
    float ev = er[r2];
    float4 p = *(const float4*)(P + (size_t)r2*EMB_ + e);
    acc.x += ev*p.x; acc.y += ev*p.y; acc.z += ev*p.z; acc.w += ev*p.w;
  }
  size_t o = (size_t)blk*EMB_ + e;
  embb[o+0]=(__bf16)acc.x; embb[o+1]=(__bf16)acc.y;
  embb[o+2]=(__bf16)acc.z; embb[o+3]=(__bf16)acc.w;
}

// ---------------- pack [W;U] into per-block LDS-resident frag order ----------------
__global__ void k_pack2(const float* __restrict__ W, int K1, const float* __restrict__ U,
                        __bf16* __restrict__ dst, int NCH){
  int ch = blockIdx.x;            // k-chunk (32 rows)
  int g  = blockIdx.y >> 2;       // gate 0..3
  int band = blockIdx.y & 3;      // 256-col band within the gate
  int tid = threadIdx.x;          // 256 threads
  __shared__ __bf16 Tl[32][264];
  {
    int r = tid>>3, cs = tid&7;   // row, col-octet (32 cols each)
    int kk = ch*32 + r;
    const float* src = (kk < K1) ? (W + (size_t)kk*G4 + g*1024 + band*256 + cs*32)
                                 : (U + (size_t)(kk-K1)*G4 + g*1024 + band*256 + cs*32);
    #pragma unroll
    for (int u=0;u<8;u++){
      float4 v = *(const float4*)(src + u*4);
      Tl[r][cs*32+u*4+0]=(__bf16)v.x; Tl[r][cs*32+u*4+1]=(__bf16)v.y;
      Tl[r][cs*32+u*4+2]=(__bf16)v.z; Tl[r][cs*32+u*4+3]=(__bf16)v.w;
    }
  }
  __syncthreads();
  int bil = tid>>2, aq = tid&3;   // 64 local blocks x 4 k-quarters
  int bi = band*64 + bil;
  #pragma unroll
  for (int q=0;q<4;q++){
    __bf16 o8[8];
    #pragma unroll
    for (int i=0;i<8;i++) o8[i] = Tl[aq*8+i][bil*4+q];
    int lane = aq*16 + g*4 + q;
    *(bf16x8*)(dst + (((size_t)bi*NCH + ch)*64 + lane)*8) = *(bf16x8*)o8;
  }
}

// ---------------- generic B-frag pack (16x16x32) for Wo / P^T ----------------
__global__ void k_packB(const float* __restrict__ src, __bf16* __restrict__ dst,
                        int K, int N, int tr){
  int kk0 = blockIdx.x*32, j0 = blockIdx.y*16, lane = threadIdx.x;  // 64 threads
  int am = lane&15, aq = lane>>4;
  int j = j0 + am;
  __bf16 o8[8];
  #pragma unroll
  for (int i=0;i<8;i++){
    int k = kk0 + aq*8 + i;
    float v = tr ? src[(size_t)j*K + k] : src[(size_t)k*N + j];
    o8[i] = (__bf16)v;
  }
  int NCH = K/32, jt = j0>>4, ch = kk0>>5;
  *(bf16x8*)(dst + (((size_t)jt*NCH + ch)*64 + lane)*8) = *(bf16x8*)o8;
}

// ---------------- chunk accumulate: NC chunks of K=32 against LDS weights ----------------
template<int NC>
__device__ __forceinline__ void accum(f32x4& acc0, f32x4& acc1,
    const __bf16* __restrict__ abase, int rs, const __bf16* wlds,
    int ch0, int am, int aq, int lane)
{
  const __bf16* a0p = abase + (size_t)am*rs + aq*8;
  const __bf16* a1p = abase + (size_t)(am+16)*rs + aq*8;
  const __bf16* wl  = wlds + (size_t)lane*8;
  #pragma unroll
  for (int c=0;c<NC;c++){
    int ch = ch0 + c;
    bf16x8 a0 = *(const bf16x8*)(a0p + (size_t)ch*32);
    bf16x8 a1 = *(const bf16x8*)(a1p + (size_t)ch*32);
    bf16x8 w  = *(const bf16x8*)(wl  + (size_t)ch*512);
    acc0 = __builtin_amdgcn_mfma_f32_16x16x32_bf16(a0, w, acc0, 0, 0, 0);
    acc1 = __builtin_amdgcn_mfma_f32_16x16x32_bf16(a1, w, acc1, 0, 0, 0);
  }
}

// ---------------- 8-wave reduce + LSTM cell (c-state in registers, packed u64 h-store) ----------------
__device__ __forceinline__ void reduce_cell(SharedU& su, const f32x4& acc0, const f32x4& acc1,
    int bi, int tid, const float* __restrict__ bias, float& creg,
    __bf16* __restrict__ hout, int stride)
{
  int kw = tid>>6, lane = tid&63, am = lane&15, aq = lane>>4;
  if (kw >= 4){
    #pragma unroll
    for (int rg=0;rg<4;rg++){
      su.r.red[kw-4][0][aq*4+rg][am] = acc0[rg];
      su.r.red[kw-4][1][aq*4+rg][am] = acc1[rg];
    }
  }
  __syncthreads();
  if (kw < 4){
    #pragma unroll
    for (int rg=0;rg<4;rg++){
      su.r.red[kw][0][aq*4+rg][am] += acc0[rg];
      su.r.red[kw][1][aq*4+rg][am] += acc1[rg];
    }
  }
  __syncthreads();
  if (tid < 128){
    int b = tid>>2, q = tid&3;
    int mt = b>>4, r = b&15;
    float G0=0.f, G1=0.f, G2=0.f, G3=0.f;
    #pragma unroll
    for (int w2=0; w2<4; w2++){
      G0 += su.r.red[w2][mt][r][q];
      G1 += su.r.red[w2][mt][r][4+q];
      G2 += su.r.red[w2][mt][r][8+q];
      G3 += su.r.red[w2][mt][r][12+q];
    }
    int j = bi*4 + q;
    float gi = G0 + bias[j];
    float gf = G1 + bias[1024 + j];
    float gg = G2 + bias[2048 + j];
    float go = G3 + bias[3072 + j];
    float ii = sigmoidf_(gi), ff = sigmoidf_(gf), gv = tanhf(gg), oo = sigmoidf_(go);
    float cv = ff*creg + ii*gv;
    float hv = oo*tanhf(cv);
    creg = cv;
    union { __bf16 h; unsigned short s; } hu; hu.h = (__bf16)hv;
    unsigned h0v = hu.s;
    unsigned h1v = __shfl_down(h0v, 1);
    unsigned h2v = __shfl_down(h0v, 2);
    unsigned h3v = __shfl_down(h0v, 3);
    if (q == 0){
      unsigned long long pk = (unsigned long long)(h0v & 0xffffu)
                            | ((unsigned long long)(h1v & 0xffffu) << 16)
                            | ((unsigned long long)(h2v & 0xffffu) << 32)
                            | ((unsigned long long)(h3v & 0xffffu) << 48);
      stc_u64(hout + (size_t)b*stride + bi*4, pk);
    }
  }
}

// ---------------- attention for one batch row, split PV half (512 threads) ----------------
__device__ __forceinline__ void attn_block(AttnShared& sa, int b, int chalf, int tid,
    const __bf16* __restrict__ encb, const int* __restrict__ enc_lens,
    __bf16* __restrict__ fbt)
{
  if (tid < 128){
    bf16x8 h8 = *(const bf16x8*)(fbt + (size_t)b*2048 + tid*8);
    #pragma unroll
    for (int u=0;u<8;u++) sa.u.hS[tid*8+u] = b2f(h8[u]);
  }
  __syncthreads();
  int w = tid >> 6, lane = tid & 63;
  for (int s = w; s < S_; s += 8){
    const __bf16* er = encb + ((size_t)s*32 + b)*C_;
    float a = 0.f;
    #pragma unroll
    for (int half = 0; half < 2; half++){
      int k = lane*8 + half*512;
      bf16x8 e8 = *(const bf16x8*)(er + k);
      #pragma unroll
      for (int u=0;u<8;u++) a += b2f(e8[u]) * sa.u.hS[k+u];
    }
    #pragma unroll
    for (int off=32; off>0; off>>=1) a += __shfl_down(a, off);
    if (lane == 0) sa.sS[s] = a;
  }
  __syncthreads();
  if (tid < 64){
    int len = enc_lens[b];
    float sc = (tid < len && tid < S_) ? sa.sS[tid] : -1e30f;
    float m = sc;
    #pragma unroll
    for (int off=32; off>0; off>>=1) m = fmaxf(m, __shfl_xor(m, off));
    float e = expf(sc - m);
    float ssum = e;
    #pragma unroll
    for (int off=32; off>0; off>>=1) ssum += __shfl_xor(ssum, off);
    sa.pS[tid] = e / ssum;
  }
  __syncthreads();                    // hS dead past here -> cred may overlay
  int cg = tid & 63, sg = tid >> 6;   // 8-way s-split over this block's 512-col half
  float a8[8];
  #pragma unroll
  for (int i=0;i<8;i++) a8[i] = 0.f;
  for (int s = sg; s < S_; s += 8){
    float p = sa.pS[s];
    bf16x8 e8 = *(const bf16x8*)(encb + ((size_t)s*32 + b)*C_ + chalf*512 + cg*8);
    #pragma unroll
    for (int i=0;i<8;i++) a8[i] += p * b2f(e8[i]);
  }
  if (sg > 0){
    #pragma unroll
    for (int i=0;i<8;i++) sa.u.cred[sg-1][cg][i] = a8[i];
  }
  __syncthreads();
  if (sg == 0){
    union { __bf16 bb[8]; unsigned long long u[2]; } cu;
    #pragma unroll
    for (int i=0;i<8;i++){
      float v = a8[i];
      #pragma unroll
      for (int k=0;k<7;k++) v += sa.u.cred[k][cg][i];
      cu.bb[i] = (__bf16)v;
    }
    stc_u64(fbt + (size_t)b*2048 + 1024 + chalf*512 + cg*8,     cu.u[0]);
    stc_u64(fbt + (size_t)b*2048 + 1024 + chalf*512 + cg*8 + 4, cu.u[1]);
  }
}

// ---------------- persistent decode loop (256 blocks x 512 threads) ----------------
// Append-only cross-block buffers (h0b[t], featsb[t]) -> plain cached loads stay fresh.
// Sync per step: pflag (direct, 64 flags) + bar1 (observer) + bar2 (direct, attn blocks only).
__global__ __launch_bounds__(512) void k_loop(
    const __bf16* __restrict__ WP0, const __bf16* __restrict__ WP1,
    const float* __restrict__ b0, const float* __restrict__ b1,
    __bf16* __restrict__ h0b,      // h0b[t] base (t=0 slot; t=-1 valid below)
    __bf16* __restrict__ featsb,   // featsb[t] base (t=-1 valid below)
    const __bf16* __restrict__ embb,
    const __bf16* __restrict__ encb, const int* __restrict__ enc_lens,
    unsigned* bars)
{
  __shared__ __bf16 wB0[80*512];   // 81920 B : gemm0 weight slice (N=16 gate-cols, K=2560)
  __shared__ __bf16 wB1[64*512];   // 65536 B : gemm1 weight slice (N=16, K=2048)
  __shared__ SharedU su;           // reduce / attention overlay
  int bi = blockIdx.x, tid = threadIdx.x;
  int kw = tid>>6, lane = tid&63, am = lane&15, aq = lane>>4;

  // one-time weight load into LDS
  {
    const bf16x8* g0 = (const bf16x8*)(WP0 + (size_t)bi*80*512);
    const bf16x8* g1 = (const bf16x8*)(WP1 + (size_t)bi*64*512);
    bf16x8* l0 = (bf16x8*)wB0;
    bf16x8* l1 = (bf16x8*)wB1;
    for (int idx = tid; idx < 80*64; idx += 512) l0[idx] = g0[idx];
    for (int idx = tid; idx < 64*64; idx += 512) l1[idx] = g1[idx];
  }
  __syncthreads();

  float c0r = 0.f, c1r = 0.f;
  f32x4 g00 = z4(), g01 = z4(), g10 = z4(), g11 = z4();

  // prologue: gates0(t=0) partial = emb_0 @ W0e + h0_init @ U0
  accum<2>(g00, g01, embb,                 512,  wB0, kw*2,    am, aq, lane);
  accum<4>(g00, g01, h0b - 32768 - 1536,   1024, wB0, 48+kw*4, am, aq, lane);

  unsigned e = 0;
  for (int t = 0; t < TS; t++){
    const __bf16* fprev = featsb + ((size_t)(t-1))*65536;  // [h1_{t-1}(1024), ctx_t(1024)]
    __bf16* h0t = h0b + (size_t)t*32768;
    __bf16* ft  = featsb + (size_t)t*65536;

    // ---- phase 1: + ctx part -> gates0 -> cell0 -> h0_t ----
    pflag_wait(bars, (unsigned)t);
    accum<4>(g00, g01, fprev + 512, 2048, wB0, 16+kw*4, am, aq, lane);
    reduce_cell(su, g00, g01, bi, tid, b0, c0r, h0t, 1024);
    g00 = z4(); g01 = z4();
    bar_arrive(bars, bi, ++e);
    // spin-work: gates1 partial U1 @ h1_{t-1}
    accum<4>(g10, g11, fprev - 1024, 2048, wB1, 32+kw*4, am, aq, lane);
    bar_wait_all(bars, bi, e);

    // ---- phase 2: + W1 @ h0_t -> gates1 -> cell1 -> h1_t ----
    accum<4>(g10, g11, h0t, 1024, wB1, kw*4, am, aq, lane);
    reduce_cell(su, g10, g11, bi, tid, b1, c1r, ft, 2048);
    g10 = z4(); g11 = z4();
    bar_arrive(bars, bi, ++e);
    // spin-work: gates0(t+1) partial = emb_{t+1} @ W0 + h0_t @ U0
    if (t + 1 < TS){
      accum<2>(g00, g01, embb + (size_t)(t+1)*16384, 512,  wB0, kw*2,    am, aq, lane);
      accum<4>(g00, g01, h0t - 1536,                 1024, wB0, 48+kw*4, am, aq, lane);
    }

    // ---- phase 3: attention (64 blocks; only they wait for h1) ----
    if (bi < 64){
      bar_wait_direct(bars, e);
      attn_block(su.a, bi & 31, bi >> 5, tid, encb, enc_lens, ft);
      asm volatile("s_waitcnt vmcnt(0)" ::: "memory");
      __syncthreads();
      if (tid == 0)
        __hip_atomic_store(bars + FL_P + (size_t)bi*32, (unsigned)(t+1), __ATOMIC_RELAXED, AG);
    }
  }
}

// ---------------- hproj = tanh(featsb @ WoP + bo) -> hpb (bf16 MFMA) ----------------
__global__ __launch_bounds__(256) void k_hproj_mfma(
    const __bf16* __restrict__ fb, const __bf16* __restrict__ WoP,
    const float* __restrict__ bo, __bf16* __restrict__ hpb)
{
  int nt = blockIdx.x, jb = blockIdx.y, tid = threadIdx.x;  // (47,16)
  int w = tid>>6, lane = tid&63;
  int mt = w&1, jw = w>>1;
  int am = lane&15, aq = lane>>4;
  const __bf16* aRow = fb + ((size_t)(nt*32 + mt*16 + am))*2048 + aq*8;
  int jt = jb*2 + jw;
  const __bf16* bptr = WoP + ((size_t)jt*64)*512 + lane*8;
  f32x4 acc = {0,0,0,0};
  bf16x8 ar0 = *(const bf16x8*)(aRow);
  bf16x8 br0 = *(const bf16x8*)(bptr);
  bf16x8 ar1 = *(const bf16x8*)(aRow + 32);
  bf16x8 br1 = *(const bf16x8*)(bptr + 512);
  for (int ch = 0; ch < 64; ch += 2){
    bf16x8 a0 = ar0, b0 = br0, a1 = ar1, b1 = br1;
    if (ch + 2 < 64){
      ar0 = *(const bf16x8*)(aRow + (ch+2)*32);
      br0 = *(const bf16x8*)(bptr + (size_t)(ch+2)*512);
      ar1 = *(const bf16x8*)(aRow + (ch+3)*32);
      br1 = *(const bf16x8*)(bptr + (size_t)(ch+3)*512);
    }
    acc = __builtin_amdgcn_mfma_f32_16x16x32_bf16(a0, b0, acc, 0, 0, 0);
    acc = __builtin_amdgcn_mfma_f32_16x16x32_bf16(a1, b1, acc, 0, 0, 0);
  }
  int jcol = jb*32 + jw*16 + am;
  float bv = bo[jcol];
  #pragma unroll
  for (int rg=0; rg<4; rg++){
    int m = nt*32 + mt*16 + aq*4 + rg;
    hpb[(size_t)m*512 + jcol] = (__bf16)tanhf(acc[rg] + bv);
  }
}

// ---------------- r = hpb @ P^T -> rbuf (bf16 MFMA) ----------------
__global__ __launch_bounds__(256) void k_rproj_mfma(
    const __bf16* __restrict__ hpb, const __bf16* __restrict__ PP,
    __bf16* __restrict__ rb)
{
  int nt = blockIdx.x, jb = blockIdx.y, tid = threadIdx.x;  // (47,4)
  int w = tid>>6, lane = tid&63;
  int mt = w&1, jw = w>>1;
  int am = lane&15, aq = lane>>4;
  const __bf16* aRow = hpb + ((size_t)(nt*32 + mt*16 + am))*512 + aq*8;
  int jt = jb*2 + jw;
  const __bf16* bptr = PP + ((size_t)jt*16)*512 + lane*8;
  f32x4 acc = {0,0,0,0};
  #pragma unroll
  for (int ch = 0; ch < 16; ch++){
    bf16x8 a = *(const bf16x8*)(aRow + ch*32);
    bf16x8 b = *(const bf16x8*)(bptr + (size_t)ch*512);
    acc = __builtin_amdgcn_mfma_f32_16x16x32_bf16(a, b, acc, 0, 0, 0);
  }
  int jcol = jb*32 + jw*16 + am;
  #pragma unroll
  for (int rg=0; rg<4; rg++){
    int m = nt*32 + mt*16 + aq*4 + rg;
    rb[(size_t)m*RANK_ + jcol] = (__bf16)acc[rg];
  }
}

// ---------------- vocab GEMM: grid 250 v-chunks, loop all 47 n-tiles ----------------
__global__ __launch_bounds__(256) void k_vocab2(
    const __bf16* __restrict__ rb, const __bf16* __restrict__ Eb,
    const int* __restrict__ tok,
    float* __restrict__ mpart, float* __restrict__ lpart,
    float* __restrict__ lablog)
{
  int vc = blockIdx.x, tid = threadIdx.x;
  int w = tid>>6, lane = tid&63;
  int am = lane&15, aq = lane>>4;
  int vb = vc*128 + w*32;
  bf16x8 bfr[2][4];
  #pragma unroll
  for (int vt=0; vt<2; vt++)
    #pragma unroll
    for (int ks=0; ks<4; ks++)
      bfr[vt][ks] = *(const bf16x8*)(Eb + ((size_t)(vb + vt*16 + am))*RANK_ + ks*32 + aq*8);

  __shared__ float redM[4][32], redL[4][32];
  for (int nt = 0; nt < TS; nt++){
    f32x4 acc[2][2] = {{{0,0,0,0},{0,0,0,0}},{{0,0,0,0},{0,0,0,0}}};
    #pragma unroll
    for (int mt=0; mt<2; mt++){
      #pragma unroll
      for (int ks=0; ks<4; ks++){
        bf16x8 a = *(const bf16x8*)(rb + ((size_t)(nt*32 + mt*16 + am))*RANK_ + ks*32 + aq*8);
        acc[mt][0] = __builtin_amdgcn_mfma_f32_16x16x32_bf16(a, bfr[0][ks], acc[mt][0], 0,0,0);
        acc[mt][1] = __builtin_amdgcn_mfma_f32_16x16x32_bf16(a, bfr[1][ks], acc[mt][1], 0,0,0);
      }
    }
    #pragma unroll
    for (int mt=0; mt<2; mt++){
      #pragma unroll
      for (int rg=0; rg<4; rg++){
        int row = mt*16 + aq*4 + rg;
        int n = nt*32 + row;
        int lbl = tok[row*T_ + nt + 1];
        float v0 = acc[mt][0][rg], v1 = acc[mt][1][rg];
        if (vb + am == lbl)      lablog[n] = v0;
        if (vb + 16 + am == lbl) lablog[n] = v1;
        float m = fmaxf(v0, v1);
        #pragma unroll
        for (int off=1; off<16; off<<=1) m = fmaxf(m, __shfl_xor(m, off));
        float l = expf(v0 - m) + expf(v1 - m);
        #pragma unroll
        for (int off=1; off<16; off<<=1) l += __shfl_xor(l, off);
        if (am == 0){ redM[w][row] = m; redL[w][row] = l; }
      }
    }
    __syncthreads();
    if (tid < 32){
      float M = fmaxf(fmaxf(redM[0][tid], redM[1][tid]), fmaxf(redM[2][tid], redM[3][tid]));
      float L = 0.f;
      #pragma unroll
      for (int ww=0; ww<4; ww++) L += redL[ww][tid]*expf(redM[ww][tid] - M);
      mpart[(size_t)(nt*32 + tid)*250 + vc] = M;
      lpart[(size_t)(nt*32 + tid)*250 + vc] = L;
    }
    __syncthreads();
  }
}

// ---------------- loss stage 1 ----------------
__global__ void k_loss1(const float* __restrict__ mpart, const float* __restrict__ lpart,
                        const float* __restrict__ lablog, const int* __restrict__ tgt_lens,
                        float* __restrict__ tpart){
  int t = blockIdx.x, tid = threadIdx.x;
  int row = tid >> 3, cq = tid & 7;
  int n = t*32 + row;
  float m = -1e30f;
  for (int c = cq; c < 250; c += 8) m = fmaxf(m, mpart[(size_t)n*250 + c]);
  #pragma unroll
  for (int off=1; off<8; off<<=1) m = fmaxf(m, __shfl_xor(m, off));
  float l = 0.f;
  for (int c = cq; c < 250; c += 8) l += lpart[(size_t)n*250 + c]*expf(mpart[(size_t)n*250 + c] - m);
  #pragma unroll
  for (int off=1; off<8; off<<=1) l += __shfl_xor(l, off);
  __shared__ float red[32];
  if (cq == 0)
    red[row] = (t < tgt_lens[row] - 1) ? (m + logf(l) - lablog[n]) : 0.f;
  __syncthreads();
  if (tid == 0){
    float s = 0.f;
    #pragma unroll
    for (int i=0;i<32;i++) s += red[i];
    tpart[t] = s;
  }
}

// ---------------- loss stage 2 ----------------
__global__ void k_loss2(const float* __restrict__ tpart, float* __restrict__ out){
  int tid = threadIdx.x;
  float v = (tid < TS) ? tpart[tid] : 0.f;
  #pragma unroll
  for (int off=32; off>0; off>>=1) v += __shfl_down(v, off);
  if (tid == 0) out[0] = v;
}

extern "C" void kernel_launch(void* const* d_in, const int* in_sizes, int n_in,
                              void* d_out, int out_size, void* d_ws, size_t ws_size,
                              hipStream_t stream){
  const float* enc      = (const float*)d_in[0];
  const float* es       = (const float*)d_in[1];
  const int*   tok      = (const int*)  d_in[2];
  const int*   enc_lens = (const int*)  d_in[3];
  const int*   tgt_lens = (const int*)  d_in[4];
  const float* E        = (const float*)d_in[5];
  const float* P        = (const float*)d_in[6];
  const float* W0       = (const float*)d_in[7];
  const float* U0       = (const float*)d_in[8];
  const float* b0       = (const float*)d_in[9];
  const float* W1       = (const float*)d_in[10];
  const float* U1       = (const float*)d_in[11];
  const float* b1       = (const float*)d_in[12];
  const float* Wo       = (const float*)d_in[13];
  const float* bo       = (const float*)d_in[14];
  float* out = (float*)d_out;

  float* fb = (float*)d_ws;
  size_t fo = 0;
  float* mpart = fb + fo; fo += (size_t)TS*32*250;
  float* lpart = fb + fo; fo += (size_t)TS*32*250;
  float* lab   = fb + fo; fo += (size_t)TS*32;
  float* tpart = fb + fo; fo += 64;
  unsigned* bars = (unsigned*)(fb + fo); fo += FL_SIZE;
  __bf16* bb = (__bf16*)(fb + fo);
  size_t bo2 = 0;
  __bf16* WP0    = bb + bo2; bo2 += (size_t)4096*2560;   // dead after k_loop's LDS load
  __bf16* WP1    = bb + bo2; bo2 += (size_t)4096*2048;
  __bf16* encb   = bb + bo2; bo2 += (size_t)S_*32*C_;
  __bf16* embb   = bb + bo2; bo2 += (size_t)TS*32*EMB_;
  __bf16* rbuf   = bb + bo2; bo2 += (size_t)TS*32*RANK_;
  __bf16* WoP    = bb + bo2; bo2 += (size_t)2048*512;
  __bf16* PP     = bb + bo2; bo2 += (size_t)512*128;
  __bf16* featsb0= bb + bo2; bo2 += (size_t)(TS+1)*32*2048;   // slot -1 + 47 steps
  __bf16* hpb    = bb + bo2; bo2 += (size_t)TS*32*EMB_;
  __bf16* h0b0   = bb + bo2; bo2 += (size_t)(TS+1)*32*1024;   // slot -1 + 47 steps
  __bf16* Eb     = WP0;      // ALIAS: converted after k_loop (WP0 dead), used by k_vocab2

  __bf16* featsb = featsb0 + (size_t)32*2048;   // featsb[t], t>=0; [-1] = featsb0
  __bf16* h0b    = h0b0 + (size_t)32*1024;

  k_init<<<128, 256, 0, stream>>>(es, h0b0, featsb0, bars);
  k_cvt<<<(S_*32*C_/4 + 255)/256, 256, 0, stream>>>(enc, encb, S_*32*C_);
  k_embed<<<TS*32, 128, 0, stream>>>(E, P, tok, embb);
  k_pack2<<<dim3(80,16), 256, 0, stream>>>(W0, 1536, U0, WP0, 80);
  k_pack2<<<dim3(64,16), 256, 0, stream>>>(W1, 1024, U1, WP1, 64);
  k_packB<<<dim3(64,32), 64, 0, stream>>>(Wo, WoP, 2048, 512, 0);
  k_packB<<<dim3(16,8), 64, 0, stream>>>(P, PP, 512, 128, 1);

  k_loop<<<NBLK, 512, 0, stream>>>(WP0, WP1, b0, b1, h0b, featsb,
                                   embb, encb, enc_lens, bars);

  // E -> bf16 AFTER k_loop (Eb aliases WP0, which is dead past the LDS weight load)
  k_cvt<<<(VOCAB_*RANK_/4 + 255)/256, 256, 0, stream>>>(E, Eb, VOCAB_*RANK_);

  k_hproj_mfma<<<dim3(TS,16), 256, 0, stream>>>(featsb, WoP, bo, hpb);
  k_rproj_mfma<<<dim3(TS,4), 256, 0, stream>>>(hpb, PP, rbuf);
  k_vocab2<<<250, 256, 0, stream>>>(rbuf, Eb, tok, mpart, lpart, lab);
  k_loss1<<<TS, 256, 0, stream>>>(mpart, lpart, lab, tgt_lens, tpart);
  k_loss2<<<1, 64, 0, stream>>>(tpart, out);
}